// Round 9
// baseline (519.249 us; speedup 1.0000x reference)
//
#include <hip/hip_runtime.h>
#include <hip/hip_bf16.h>

#define NEG_SLOPE 0.2f
#define BN_EPS 1e-5f

typedef __attribute__((ext_vector_type(8))) short bf16x8;
typedef __attribute__((ext_vector_type(4))) float f32x4;

__device__ __forceinline__ float bf2f(unsigned short u) {
    union { unsigned int i; float f; } x;
    x.i = ((unsigned int)u) << 16;
    return x.f;
}
__device__ __forceinline__ unsigned short f2bf(float f) {
    __hip_bfloat16 b = __float2bfloat16(f);
    return *reinterpret_cast<unsigned short*>(&b);
}
__device__ __forceinline__ float lrelu(float v) {
    return v > 0.f ? v : NEG_SLOPE * v;
}
__device__ __forceinline__ void gload_lds16(const void* g, void* l) {
    __builtin_amdgcn_global_load_lds(
        (const __attribute__((address_space(1))) unsigned int*)(g),
        (__attribute__((address_space(3))) unsigned int*)(l),
        16, 0, 0);
}

// ---------------------------------------------------------------- CSR build
__global__ __launch_bounds__(256) void count_kernel(const int* __restrict__ dstl,
                                                    int E, int N, int* __restrict__ counts) {
    int i = blockIdx.x * 256 + threadIdx.x;
    if (i < E + N) {
        int d = (i < E) ? dstl[i] : (i - E);
        atomicAdd(&counts[d], 1);
    }
}

__device__ __forceinline__ int block_scan_incl(int v, int t) {
    int lane = t & 63, w = t >> 6;
    int sv = v;
    #pragma unroll
    for (int off = 1; off < 64; off <<= 1) {
        int u = __shfl_up(sv, off);
        if (lane >= off) sv += u;
    }
    __shared__ int ws[4];
    if (lane == 63) ws[w] = sv;
    __syncthreads();
    if (t == 0) {
        int a = 0;
        #pragma unroll
        for (int k = 0; k < 4; k++) { int x = ws[k]; ws[k] = a; a += x; }
    }
    __syncthreads();
    return sv + ws[w];
}

__global__ __launch_bounds__(256) void scan1(const int* __restrict__ counts,
                                             int* __restrict__ tmp,
                                             int* __restrict__ bsums, int n) {
    int t = threadIdx.x, i = blockIdx.x * 256 + t;
    int v = (i < n) ? counts[i] : 0;
    int incl = block_scan_incl(v, t);
    if (i < n) tmp[i] = incl;
    if (t == 255) bsums[blockIdx.x] = incl;
}

__global__ __launch_bounds__(256) void scan2(int* __restrict__ bsums, int nb) {
    int t = threadIdx.x;
    int v = (t < nb) ? bsums[t] : 0;
    int incl = block_scan_incl(v, t);
    if (t < nb) bsums[t] = incl - v;
}

__global__ __launch_bounds__(256) void scan3(const int* __restrict__ tmp,
                                             const int* __restrict__ bsums,
                                             const int* __restrict__ counts,
                                             int* __restrict__ indptr,
                                             int* __restrict__ cursor, int n) {
    int i = blockIdx.x * 256 + threadIdx.x;
    if (i < n) {
        int incl = tmp[i] + bsums[i >> 8];
        indptr[i + 1] = incl;
        cursor[i] = incl - counts[i];
        if (i == 0) indptr[0] = 0;
    }
}

__global__ __launch_bounds__(256) void fill_kernel(const int* __restrict__ srcl,
                                                   const int* __restrict__ dstl,
                                                   int E, int N,
                                                   int* __restrict__ cursor,
                                                   int* __restrict__ esrc) {
    int i = blockIdx.x * 256 + threadIdx.x;
    if (i < E + N) {
        int s, d;
        if (i < E) { s = srcl[i]; d = dstl[i]; }
        else       { s = d = i - E; }
        int slot = atomicAdd(&cursor[d], 1);
        esrc[slot] = s;
    }
}

// ---------------------------------------------------------------- prep: x->bf16 + all weight transposes
__global__ __launch_bounds__(256) void prep_all(const float* __restrict__ x,
                                                unsigned short* __restrict__ xb, int n4x,
                                                const float* __restrict__ W1,
                                                const float* __restrict__ Ws1,
                                                const float* __restrict__ W2,
                                                const float* __restrict__ Ws2,
                                                const float* __restrict__ W3,
                                                unsigned short* __restrict__ Wcat1,
                                                unsigned short* __restrict__ Wcat2,
                                                unsigned short* __restrict__ W3t) {
    int i = blockIdx.x * 256 + threadIdx.x;
    if (i < n4x) {
        float4 v = reinterpret_cast<const float4*>(x)[i];
        ushort4 o;
        o.x = f2bf(v.x); o.y = f2bf(v.y); o.z = f2bf(v.z); o.w = f2bf(v.w);
        reinterpret_cast<ushort4*>(xb)[i] = o;
        return;
    }
    int j = i - n4x;
    if (j < 32768) {                       // W1^T: 256 rows x 128
        int m = j >> 7, k = j & 127;
        Wcat1[j] = f2bf(W1[k * 256 + m]);
    } else if (j < 65536) {                // Ws1^T: rows 256..511
        int q = j - 32768; int m = q >> 7, k = q & 127;
        Wcat1[32768 + q] = f2bf(Ws1[k * 256 + m]);
    } else if (j < 131072) {               // W2^T: 256 rows x 256
        int q = j - 65536; int m = q >> 8, k = q & 255;
        Wcat2[q] = f2bf(W2[k * 256 + m]);
    } else if (j < 139264) {               // Ws2^T: rows 256..287
        int q = j - 131072; int m = q >> 8, k = q & 255;
        Wcat2[65536 + q] = f2bf(Ws2[k * 32 + m]);
    } else if (j < 147456) {               // W3^T: 32 rows x 256
        int q = j - 139264; int m = q >> 8, k = q & 255;
        W3t[q] = f2bf(W3[k * 32 + m]);
    }
}

// ---------------------------------------------------------------- tiled MFMA GEMM
// C[M x NCtot] = A[M x K](bf16) @ B, Bt[NCtot x K] = B^T (bf16).
// 128x128 tile, BK=32, double-buffered LDS via global_load_lds(16B).
// Epilogue (all bf16): col < split -> outBf (no bias); col >= split -> outSk + biasSk.
__global__ __launch_bounds__(256) void gemm_tile(const unsigned short* __restrict__ A,
                                                 const unsigned short* __restrict__ Bt,
                                                 unsigned short* __restrict__ outBf,
                                                 unsigned short* __restrict__ outSk,
                                                 const float* __restrict__ biasSk,
                                                 int M, int K, int NCtot, int split,
                                                 int ldBf, int ldSk) {
    __shared__ __align__(16) char smem[2][2][8192];
    int t = threadIdx.x;
    int w = t >> 6, lane = t & 63;
    int l16 = lane & 15, quad = lane >> 4;
    int warp_r = w >> 1, warp_c = w & 1;
    int rowBase = blockIdx.y * 128;
    int colBase = blockIdx.x * 128;

    int row_l = t & 127;
    int jchunk = t >> 7;
    int arow_st = rowBase + row_l; if (arow_st >= M) arow_st = M - 1;
    int bcol_st = colBase + row_l; if (bcol_st >= NCtot) bcol_st = NCtot - 1;
    const unsigned short* aRow = A + (size_t)arow_st * K;
    const unsigned short* bRow = Bt + (size_t)bcol_st * K;

    f32x4 acc[4][4];
    #pragma unroll
    for (int i = 0; i < 4; i++)
        #pragma unroll
        for (int j = 0; j < 4; j++) acc[i][j] = (f32x4){0.f, 0.f, 0.f, 0.f};

    auto stage = [&](int buf, int k0) {
        #pragma unroll
        for (int j = 0; j < 2; j++) {
            int chunk = j * 2 + jchunk;
            gload_lds16(aRow + k0 + chunk * 8, &smem[buf][0][(size_t)j * 4096 + (size_t)t * 16]);
            gload_lds16(bRow + k0 + chunk * 8, &smem[buf][1][(size_t)j * 4096 + (size_t)t * 16]);
        }
    };

    stage(0, 0);
    __syncthreads();
    int niter = K >> 5;
    for (int it = 0; it < niter; ++it) {
        if (it + 1 < niter) stage((it + 1) & 1, (it + 1) << 5);
        const char* Ab = &smem[it & 1][0][0];
        const char* Bb = &smem[it & 1][1][0];
        bf16x8 a[4], b[4];
        #pragma unroll
        for (int i = 0; i < 4; i++)
            a[i] = *reinterpret_cast<const bf16x8*>(Ab + quad * 2048 + (warp_r * 64 + i * 16 + l16) * 16);
        #pragma unroll
        for (int j = 0; j < 4; j++)
            b[j] = *reinterpret_cast<const bf16x8*>(Bb + quad * 2048 + (warp_c * 64 + j * 16 + l16) * 16);
        #pragma unroll
        for (int i = 0; i < 4; i++)
            #pragma unroll
            for (int j = 0; j < 4; j++)
                acc[i][j] = __builtin_amdgcn_mfma_f32_16x16x32_bf16(a[i], b[j], acc[i][j], 0, 0, 0);
        __syncthreads();
    }

    #pragma unroll
    for (int i = 0; i < 4; i++) {
        #pragma unroll
        for (int r = 0; r < 4; r++) {
            int row = rowBase + warp_r * 64 + i * 16 + quad * 4 + r;
            if (row >= M) continue;
            #pragma unroll
            for (int j = 0; j < 4; j++) {
                int c = colBase + warp_c * 64 + j * 16 + l16;
                if (c >= NCtot) continue;
                float v = acc[i][j][r];
                if (c < split) outBf[(size_t)row * ldBf + c] = f2bf(v);
                else           outSk[(size_t)row * ldSk + (c - split)] = f2bf(v + biasSk[c - split]);
            }
        }
    }
}

// ---------------------------------------------------------------- alpha (H=8,C=32), wave/node
__global__ __launch_bounds__(256) void alpha256(const unsigned short* __restrict__ h,
                                                const float* __restrict__ a_s,
                                                const float* __restrict__ a_d,
                                                float* __restrict__ as_out,
                                                float* __restrict__ ad_out, int N) {
    int t = threadIdx.x;
    int n = blockIdx.x * 4 + (t >> 6);
    if (n >= N) return;
    int lane = t & 63, lane4 = lane * 4;
    ushort4 hv = *reinterpret_cast<const ushort4*>(&h[(size_t)n * 256 + lane4]);
    float4 sv = *reinterpret_cast<const float4*>(&a_s[lane4]);
    float4 dv = *reinterpret_cast<const float4*>(&a_d[lane4]);
    float h0 = bf2f(hv.x), h1 = bf2f(hv.y), h2 = bf2f(hv.z), h3 = bf2f(hv.w);
    float va = h0 * sv.x + h1 * sv.y + h2 * sv.z + h3 * sv.w;
    float vd = h0 * dv.x + h1 * dv.y + h2 * dv.z + h3 * dv.w;
    #pragma unroll
    for (int off = 1; off < 8; off <<= 1) {
        va += __shfl_xor(va, off);
        vd += __shfl_xor(vd, off);
    }
    if ((lane & 7) == 0) {
        as_out[n * 8 + (lane >> 3)] = va;
        ad_out[n * 8 + (lane >> 3)] = vd;
    }
}

// ---------------------------------------------------------------- alpha (H=1,C=32), 8 nodes/wave
__global__ __launch_bounds__(256) void alpha32(const unsigned short* __restrict__ h,
                                               const float* __restrict__ a_s,
                                               const float* __restrict__ a_d,
                                               float* __restrict__ as_out,
                                               float* __restrict__ ad_out, int N) {
    int t = threadIdx.x;
    int lane = t & 63;
    int n = blockIdx.x * 32 + (t >> 6) * 8 + (lane >> 3);
    int c4 = (lane & 7) * 4;
    if (n >= N) return;
    ushort4 hv = *reinterpret_cast<const ushort4*>(&h[(size_t)n * 32 + c4]);
    float4 sv = *reinterpret_cast<const float4*>(&a_s[c4]);
    float4 dv = *reinterpret_cast<const float4*>(&a_d[c4]);
    float h0 = bf2f(hv.x), h1 = bf2f(hv.y), h2 = bf2f(hv.z), h3 = bf2f(hv.w);
    float va = h0 * sv.x + h1 * sv.y + h2 * sv.z + h3 * sv.w;
    float vd = h0 * dv.x + h1 * dv.y + h2 * dv.z + h3 * dv.w;
    #pragma unroll
    for (int off = 1; off < 8; off <<= 1) {
        va += __shfl_xor(va, off);
        vd += __shfl_xor(vd, off);
    }
    if ((lane & 7) == 0) {
        as_out[n] = va;
        ad_out[n] = vd;
    }
}

// ---------------------------------------------------------------- aggregation H=8,C=32
// XCD channel-split: even blockIdx.x -> channels 0..127, odd -> 128..255.
// Workgroups round-robin across XCDs, so each parity class (= channel half)
// lands on a disjoint XCD set -> per-XCD L2 working set halves (25.6->12.8MB)
// -> higher L2 hit rate -> less L3 traffic. Lane owns 2 channels (ushort2).
// Weight chain (esrc/as, L2-resident) is computed by both halves.
template <int MODE>
__global__ __launch_bounds__(256) void agg256(const unsigned short* __restrict__ hfeat,
                                              const float* __restrict__ as,
                                              const float* __restrict__ ad,
                                              const int* __restrict__ indptr,
                                              const int* __restrict__ esrc,
                                              const float* __restrict__ bias,
                                              const float* __restrict__ bn_g,
                                              const float* __restrict__ bn_b,
                                              const float* __restrict__ bn_m,
                                              const float* __restrict__ bn_v,
                                              const unsigned short* __restrict__ skip,
                                              unsigned short* __restrict__ out, int N) {
    int t = threadIdx.x;
    int bx = blockIdx.x;
    int half = bx & 1;
    int n = (bx >> 1) * 4 + (t >> 6);
    if (n >= N) return;
    int lane = t & 63;
    int e_sub = lane >> 3, h_sub = lane & 7;
    int cb = half * 128 + lane * 2;        // this lane's 2 channels
    int ch_head = cb >> 5;                  // head owning them
    int start = indptr[n], end = indptr[n + 1];
    int cnt = end - start;

    float adh = ad[n * 8 + h_sub];

    float a0 = 0.f, a1 = 0.f;
    float sm = 0.f;
    int nfull = cnt & ~7;
    int i0 = start;
    int s_l = 0; float w8 = 0.f;
    if (nfull) {
        s_l = esrc[i0 + e_sub];
        w8 = __expf(lrelu(as[s_l * 8 + h_sub] + adh));
    }
    while (i0 < start + nfull) {
        int s_cur = s_l;
        float w_cur = w8;
        i0 += 8;
        if (i0 < start + nfull) {           // prefetch next weight chain
            s_l = esrc[i0 + e_sub];
            w8 = __expf(lrelu(as[s_l * 8 + h_sub] + adh));
        }
        sm += w_cur;
        ushort2 hv[8];
        #pragma unroll
        for (int e = 0; e < 8; e++) {
            int se = __shfl(s_cur, e * 8);
            hv[e] = *reinterpret_cast<const ushort2*>(&hfeat[(size_t)se * 256 + cb]);
        }
        #pragma unroll
        for (int e = 0; e < 8; e++) {
            float we = __shfl(w_cur, e * 8 + ch_head);
            a0 = fmaf(we, bf2f(hv[e].x), a0);
            a1 = fmaf(we, bf2f(hv[e].y), a1);
        }
    }
    int rem = cnt - nfull;
    if (rem) {
        int idx = i0 + e_sub;
        int s_r = esrc[idx < end ? idx : end - 1];
        float w_r = (idx < end) ? __expf(lrelu(as[s_r * 8 + h_sub] + adh)) : 0.f;
        sm += w_r;
        #pragma unroll
        for (int e = 0; e < 8; e++) {
            if (e < rem) {
                int se = __shfl(s_r, e * 8);
                float we = __shfl(w_r, e * 8 + ch_head);
                ushort2 hv = *reinterpret_cast<const ushort2*>(&hfeat[(size_t)se * 256 + cb]);
                a0 = fmaf(we, bf2f(hv.x), a0);
                a1 = fmaf(we, bf2f(hv.y), a1);
            }
        }
    }
    #pragma unroll
    for (int off = 8; off < 64; off <<= 1) sm += __shfl_xor(sm, off);
    float il = 1.f / (sm + 1e-16f);
    float il_c = __shfl(il, ch_head);      // lane ch_head holds h_sub == ch_head

    float2 bv  = *reinterpret_cast<const float2*>(&bias[cb]);
    float2 gv  = *reinterpret_cast<const float2*>(&bn_g[cb]);
    float2 bbv = *reinterpret_cast<const float2*>(&bn_b[cb]);
    float2 mv  = *reinterpret_cast<const float2*>(&bn_m[cb]);
    float2 vv  = *reinterpret_cast<const float2*>(&bn_v[cb]);
    float o0 = a0 * il_c + bv.x;
    float o1 = a1 * il_c + bv.y;
    float sk0 = 0.f, sk1 = 0.f;
    if (MODE == 1) {
        ushort2 s2 = *reinterpret_cast<const ushort2*>(&skip[(size_t)n * 256 + cb]);
        sk0 = bf2f(s2.x); sk1 = bf2f(s2.y);
    }
    float v0 = (o0 - mv.x) * rsqrtf(vv.x + BN_EPS) * gv.x + bbv.x;
    v0 = v0 > 0.f ? v0 : (__expf(v0) - 1.f);
    v0 += sk0;
    float v1 = (o1 - mv.y) * rsqrtf(vv.y + BN_EPS) * gv.y + bbv.y;
    v1 = v1 > 0.f ? v1 : (__expf(v1) - 1.f);
    v1 += sk1;
    ushort2 res;
    res.x = f2bf(v0); res.y = f2bf(v1);
    *reinterpret_cast<ushort2*>(&out[(size_t)n * 256 + cb]) = res;
}

// ---------------------------------------------------------------- aggregation H=1,C=32
__global__ __launch_bounds__(256) void agg32(const unsigned short* __restrict__ h3,
                                             const float* __restrict__ as,
                                             const float* __restrict__ ad,
                                             const int* __restrict__ indptr,
                                             const int* __restrict__ esrc,
                                             const float* __restrict__ b3,
                                             const unsigned short* __restrict__ xs,
                                             float* __restrict__ out, int N) {
    int t = threadIdx.x;
    int n = blockIdx.x * 4 + (t >> 6);
    if (n >= N) return;
    int lane = t & 63;
    int e_sub = lane >> 3, c4 = (lane & 7) * 4;
    int start = indptr[n], end = indptr[n + 1];
    float adn = ad[n];

    float4 acc = make_float4(0.f, 0.f, 0.f, 0.f);
    float sm = 0.f;
    int i0 = start;
    for (; i0 + 16 <= end; i0 += 16) {
        int sA = esrc[i0 + e_sub];
        int sB = esrc[i0 + 8 + e_sub];
        float wA = __expf(lrelu(as[sA] + adn));
        float wB = __expf(lrelu(as[sB] + adn));
        sm += wA + wB;
        ushort4 hA = *reinterpret_cast<const ushort4*>(&h3[(size_t)sA * 32 + c4]);
        ushort4 hB = *reinterpret_cast<const ushort4*>(&h3[(size_t)sB * 32 + c4]);
        acc.x = fmaf(wA, bf2f(hA.x), acc.x); acc.y = fmaf(wA, bf2f(hA.y), acc.y);
        acc.z = fmaf(wA, bf2f(hA.z), acc.z); acc.w = fmaf(wA, bf2f(hA.w), acc.w);
        acc.x = fmaf(wB, bf2f(hB.x), acc.x); acc.y = fmaf(wB, bf2f(hB.y), acc.y);
        acc.z = fmaf(wB, bf2f(hB.z), acc.z); acc.w = fmaf(wB, bf2f(hB.w), acc.w);
    }
    for (; i0 < end; i0 += 8) {
        int idx = i0 + e_sub;
        bool valid = idx < end;
        if (valid) {
            int s = esrc[idx];
            float w = __expf(lrelu(as[s] + adn));
            sm += w;
            ushort4 hv = *reinterpret_cast<const ushort4*>(&h3[(size_t)s * 32 + c4]);
            acc.x = fmaf(w, bf2f(hv.x), acc.x);
            acc.y = fmaf(w, bf2f(hv.y), acc.y);
            acc.z = fmaf(w, bf2f(hv.z), acc.z);
            acc.w = fmaf(w, bf2f(hv.w), acc.w);
        }
    }
    #pragma unroll
    for (int off = 8; off < 64; off <<= 1) {
        sm    += __shfl_xor(sm, off);
        acc.x += __shfl_xor(acc.x, off);
        acc.y += __shfl_xor(acc.y, off);
        acc.z += __shfl_xor(acc.z, off);
        acc.w += __shfl_xor(acc.w, off);
    }
    if (e_sub == 0) {
        float il = 1.f / (sm + 1e-16f);
        float4 bv = *reinterpret_cast<const float4*>(&b3[c4]);
        ushort4 xv = *reinterpret_cast<const ushort4*>(&xs[(size_t)n * 32 + c4]);
        float4 o;
        o.x = acc.x * il + bv.x + bf2f(xv.x);
        o.y = acc.y * il + bv.y + bf2f(xv.y);
        o.z = acc.z * il + bv.z + bf2f(xv.z);
        o.w = acc.w * il + bv.w + bf2f(xv.w);
        *reinterpret_cast<float4*>(&out[(size_t)n * 32 + c4]) = o;
    }
}

// ---------------------------------------------------------------- launch
extern "C" void kernel_launch(void* const* d_in, const int* in_sizes, int n_in,
                              void* d_out, int out_size, void* d_ws, size_t ws_size,
                              hipStream_t stream) {
    const float* x      = (const float*)d_in[0];
    const int*   eidx   = (const int*)  d_in[1];
    const float* W1     = (const float*)d_in[2];
    const float* a_src1 = (const float*)d_in[3];
    const float* a_dst1 = (const float*)d_in[4];
    const float* b1     = (const float*)d_in[5];
    const float* bn1_g  = (const float*)d_in[6];
    const float* bn1_b  = (const float*)d_in[7];
    const float* bn1_m  = (const float*)d_in[8];
    const float* bn1_v  = (const float*)d_in[9];
    const float* W2     = (const float*)d_in[10];
    const float* a_src2 = (const float*)d_in[11];
    const float* a_dst2 = (const float*)d_in[12];
    const float* b2     = (const float*)d_in[13];
    const float* bn2_g  = (const float*)d_in[14];
    const float* bn2_b  = (const float*)d_in[15];
    const float* bn2_m  = (const float*)d_in[16];
    const float* bn2_v  = (const float*)d_in[17];
    const float* W3     = (const float*)d_in[18];
    const float* a_src3 = (const float*)d_in[19];
    const float* a_dst3 = (const float*)d_in[20];
    const float* b3     = (const float*)d_in[21];
    const float* Ws1    = (const float*)d_in[22];
    const float* bs1    = (const float*)d_in[23];
    const float* Ws2    = (const float*)d_in[24];
    const float* bs2    = (const float*)d_in[25];

    const int N = in_sizes[0] / 128;   // 50000
    const int E = in_sizes[1] / 2;     // 800000
    const int Etot = E + N;
    const int* srcl = eidx;
    const int* dstl = eidx + E;

    char* ws = (char*)d_ws;
    size_t off = 0;
    auto alloc = [&](size_t bytes) -> void* {
        void* p = ws + off;
        off += (bytes + 255) & ~(size_t)255;
        return p;
    };
    unsigned short* xb    = (unsigned short*)alloc((size_t)N * 128 * 2);
    unsigned short* feat  = (unsigned short*)alloc((size_t)N * 256 * 2); // x0 skip (bf16)
    unsigned short* hbuf  = (unsigned short*)alloc((size_t)N * 256 * 2); // gemm h output
    unsigned short* h2b   = (unsigned short*)alloc((size_t)N * 256 * 2); // layer-1 agg out
    unsigned short* featb = (unsigned short*)alloc((size_t)N * 256 * 2); // layer-2 agg out
    unsigned short* xsbuf = (unsigned short*)alloc((size_t)N * 32 * 2);  // xs skip (bf16)
    unsigned short* h3b   = (unsigned short*)alloc((size_t)N * 32 * 2);
    float*          asb   = (float*)alloc((size_t)N * 8 * 4);
    float*          adb   = (float*)alloc((size_t)N * 8 * 4);
    unsigned short* Wcat1 = (unsigned short*)alloc((size_t)512 * 128 * 2); // [W1t; Ws1t]
    unsigned short* Wcat2 = (unsigned short*)alloc((size_t)288 * 256 * 2); // [W2t; Ws2t]
    unsigned short* W3t   = (unsigned short*)alloc((size_t)32 * 256 * 2);
    int* counts = (int*)alloc((size_t)N * 4);
    int* cursor = (int*)alloc((size_t)N * 4);
    int* indptr = (int*)alloc((size_t)(N + 1) * 4);
    int* bsums  = (int*)alloc(256 * 4);
    int* esrc   = (int*)alloc((size_t)Etot * 4);
    (void)ws_size; (void)n_in; (void)out_size;

    // ---- CSR by dst
    hipMemsetAsync(counts, 0, (size_t)N * 4, stream);
    int ceb = (Etot + 255) / 256;
    int nb  = (N + 255) / 256;
    count_kernel<<<ceb, 256, 0, stream>>>(dstl, E, N, counts);
    scan1<<<nb, 256, 0, stream>>>(counts, cursor, bsums, N);
    scan2<<<1, 256, 0, stream>>>(bsums, nb);
    scan3<<<nb, 256, 0, stream>>>(cursor, bsums, counts, indptr, cursor, N);
    fill_kernel<<<ceb, 256, 0, stream>>>(srcl, dstl, E, N, cursor, esrc);

    // ---- convert inputs (x -> bf16, weights -> transposed bf16) in one dispatch
    int n4x = N * 128 / 4;
    prep_all<<<(n4x + 147456 + 255) / 256, 256, 0, stream>>>(x, xb, n4x,
                                                             W1, Ws1, W2, Ws2, W3,
                                                             Wcat1, Wcat2, W3t);

    int gy128 = (N + 127) / 128;
    int gn4 = (N + 3) / 4;
    int gagg = gn4 * 2;                    // x2: channel-half parity blocks

    // ---- layer 1: fused [h1 | x0] = x @ [W1 | Ws1]
    gemm_tile<<<dim3(4, gy128), 256, 0, stream>>>(xb, Wcat1, hbuf, feat, bs1,
                                                  N, 128, 512, 256, 256, 256);
    alpha256<<<gn4, 256, 0, stream>>>(hbuf, a_src1, a_dst1, asb, adb, N);
    agg256<1><<<gagg, 256, 0, stream>>>(hbuf, asb, adb, indptr, esrc, b1,
                                        bn1_g, bn1_b, bn1_m, bn1_v, feat, h2b, N);

    // ---- layer 2: fused [h2 | xs] = h @ [W2 | Ws2]
    gemm_tile<<<dim3(3, gy128), 256, 0, stream>>>(h2b, Wcat2, hbuf, xsbuf, bs2,
                                                  N, 256, 288, 256, 256, 32);
    alpha256<<<gn4, 256, 0, stream>>>(hbuf, a_src2, a_dst2, asb, adb, N);
    agg256<0><<<gagg, 256, 0, stream>>>(hbuf, asb, adb, indptr, esrc, b2,
                                        bn2_g, bn2_b, bn2_m, bn2_v, nullptr, featb, N);

    // ---- layer 3: tiled GEMM (NCtot=32; staging clamps, epilogue guards)
    gemm_tile<<<dim3(1, gy128), 256, 0, stream>>>(featb, W3t, h3b, h3b, nullptr,
                                                  N, 256, 32, 32, 32, 32);
    alpha32<<<(N + 31) / 32, 256, 0, stream>>>(h3b, a_src3, a_dst3, asb, adb, N);
    agg32<<<gn4, 256, 0, stream>>>(h3b, asb, adb, indptr, esrc, b3, xsbuf,
                                   (float*)d_out, N);
}

// Round 10
// 463.107 us; speedup vs baseline: 1.1212x; 1.1212x over previous
//
#include <hip/hip_runtime.h>
#include <hip/hip_bf16.h>

#define NEG_SLOPE 0.2f
#define BN_EPS 1e-5f

typedef __attribute__((ext_vector_type(8))) short bf16x8;
typedef __attribute__((ext_vector_type(4))) float f32x4;

#if defined(__has_builtin)
#if __has_builtin(__builtin_amdgcn_cvt_f32_fp8) && __has_builtin(__builtin_amdgcn_cvt_pk_fp8_f32)
#define HW_FP8 1
#endif
#endif

__device__ __forceinline__ float bf2f(unsigned short u) {
    union { unsigned int i; float f; } x;
    x.i = ((unsigned int)u) << 16;
    return x.f;
}
__device__ __forceinline__ unsigned short f2bf(float f) {
    __hip_bfloat16 b = __float2bfloat16(f);
    return *reinterpret_cast<unsigned short*>(&b);
}
__device__ __forceinline__ float lrelu(float v) {
    return v > 0.f ? v : NEG_SLOPE * v;
}
__device__ __forceinline__ void gload_lds16(const void* g, void* l) {
    __builtin_amdgcn_global_load_lds(
        (const __attribute__((address_space(1))) unsigned int*)(g),
        (__attribute__((address_space(3))) unsigned int*)(l),
        16, 0, 0);
}

// ---- fp8 e4m3 (OCP) encode/decode: HW path + software fallback
__device__ __forceinline__ unsigned char f8enc(float f) {
#ifdef HW_FP8
    int p = __builtin_amdgcn_cvt_pk_fp8_f32(f, 0.f, 0, false);
    return (unsigned char)(p & 0xff);
#else
    float a = fabsf(f);
    unsigned int sign = (__float_as_uint(f) >> 31) << 7;
    if (a < 0.0009765625f) return (unsigned char)sign;
    a = fminf(a, 448.f);
    unsigned int bits = __float_as_uint(a);
    int e = (int)((bits >> 23) & 0xff) - 127;
    unsigned int mant = bits & 0x7fffff;
    if (e < -6) {
        int q = (int)(a * 512.f + 0.5f);
        if (q >= 8) return (unsigned char)(sign | 0x08);
        return (unsigned char)(sign | q);
    }
    unsigned int m = mant >> 20;
    unsigned int rem = mant & 0xfffff;
    if (rem > 0x80000 || (rem == 0x80000 && (m & 1))) m++;
    if (m == 8) { m = 0; e++; }
    if (e > 8) { e = 8; m = 6; }
    return (unsigned char)(sign | ((unsigned int)(e + 7) << 3) | m);
#endif
}
template <int SEL>
__device__ __forceinline__ float f8dec(unsigned int w) {
#ifdef HW_FP8
    return __builtin_amdgcn_cvt_f32_fp8(w, SEL);
#else
    unsigned int b = (w >> (SEL * 8)) & 0xff;
    unsigned int s = b >> 7, em = b & 0x7f;
    float mag;
    if (em >= 8) {
        unsigned int bits = (((em >> 3) + 120) << 23) | ((em & 7) << 20);
        mag = __uint_as_float(bits);
    } else {
        mag = (float)em * 0.001953125f;
    }
    return s ? -mag : mag;
#endif
}

// ---------------------------------------------------------------- CSR build
__global__ __launch_bounds__(256) void count_kernel(const int* __restrict__ dstl,
                                                    int E, int N, int* __restrict__ counts) {
    int i = blockIdx.x * 256 + threadIdx.x;
    if (i < E + N) {
        int d = (i < E) ? dstl[i] : (i - E);
        atomicAdd(&counts[d], 1);
    }
}

__device__ __forceinline__ int block_scan_incl(int v, int t) {
    int lane = t & 63, w = t >> 6;
    int sv = v;
    #pragma unroll
    for (int off = 1; off < 64; off <<= 1) {
        int u = __shfl_up(sv, off);
        if (lane >= off) sv += u;
    }
    __shared__ int ws[4];
    if (lane == 63) ws[w] = sv;
    __syncthreads();
    if (t == 0) {
        int a = 0;
        #pragma unroll
        for (int k = 0; k < 4; k++) { int x = ws[k]; ws[k] = a; a += x; }
    }
    __syncthreads();
    return sv + ws[w];
}

__global__ __launch_bounds__(256) void scan1(const int* __restrict__ counts,
                                             int* __restrict__ tmp,
                                             int* __restrict__ bsums, int n) {
    int t = threadIdx.x, i = blockIdx.x * 256 + t;
    int v = (i < n) ? counts[i] : 0;
    int incl = block_scan_incl(v, t);
    if (i < n) tmp[i] = incl;
    if (t == 255) bsums[blockIdx.x] = incl;
}

__global__ __launch_bounds__(256) void scan2(int* __restrict__ bsums, int nb) {
    int t = threadIdx.x;
    int v = (t < nb) ? bsums[t] : 0;
    int incl = block_scan_incl(v, t);
    if (t < nb) bsums[t] = incl - v;
}

__global__ __launch_bounds__(256) void scan3(const int* __restrict__ tmp,
                                             const int* __restrict__ bsums,
                                             const int* __restrict__ counts,
                                             int* __restrict__ indptr,
                                             int* __restrict__ cursor, int n) {
    int i = blockIdx.x * 256 + threadIdx.x;
    if (i < n) {
        int incl = tmp[i] + bsums[i >> 8];
        indptr[i + 1] = incl;
        cursor[i] = incl - counts[i];
        if (i == 0) indptr[0] = 0;
    }
}

__global__ __launch_bounds__(256) void fill_kernel(const int* __restrict__ srcl,
                                                   const int* __restrict__ dstl,
                                                   int E, int N,
                                                   int* __restrict__ cursor,
                                                   int* __restrict__ esrc) {
    int i = blockIdx.x * 256 + threadIdx.x;
    if (i < E + N) {
        int s, d;
        if (i < E) { s = srcl[i]; d = dstl[i]; }
        else       { s = d = i - E; }
        int slot = atomicAdd(&cursor[d], 1);
        esrc[slot] = s;
    }
}

// ---------------------------------------------------------------- prep: x->bf16 + all weight transposes
__global__ __launch_bounds__(256) void prep_all(const float* __restrict__ x,
                                                unsigned short* __restrict__ xb, int n4x,
                                                const float* __restrict__ W1,
                                                const float* __restrict__ Ws1,
                                                const float* __restrict__ W2,
                                                const float* __restrict__ Ws2,
                                                const float* __restrict__ W3,
                                                unsigned short* __restrict__ Wcat1,
                                                unsigned short* __restrict__ Wcat2,
                                                unsigned short* __restrict__ W3t) {
    int i = blockIdx.x * 256 + threadIdx.x;
    if (i < n4x) {
        float4 v = reinterpret_cast<const float4*>(x)[i];
        ushort4 o;
        o.x = f2bf(v.x); o.y = f2bf(v.y); o.z = f2bf(v.z); o.w = f2bf(v.w);
        reinterpret_cast<ushort4*>(xb)[i] = o;
        return;
    }
    int j = i - n4x;
    if (j < 32768) {
        int m = j >> 7, k = j & 127;
        Wcat1[j] = f2bf(W1[k * 256 + m]);
    } else if (j < 65536) {
        int q = j - 32768; int m = q >> 7, k = q & 127;
        Wcat1[32768 + q] = f2bf(Ws1[k * 256 + m]);
    } else if (j < 131072) {
        int q = j - 65536; int m = q >> 8, k = q & 255;
        Wcat2[q] = f2bf(W2[k * 256 + m]);
    } else if (j < 139264) {
        int q = j - 131072; int m = q >> 8, k = q & 255;
        Wcat2[65536 + q] = f2bf(Ws2[k * 32 + m]);
    } else if (j < 147456) {
        int q = j - 139264; int m = q >> 8, k = q & 255;
        W3t[q] = f2bf(W3[k * 32 + m]);
    }
}

// ---------------------------------------------------------------- tiled MFMA GEMM
// 128x128 tile, BK=32, double-buffered LDS via global_load_lds(16B).
// Epilogue: col < split -> bf16 outBf (+ optional fp8 copy outQ for gathers);
//           col >= split -> bf16 outSk + biasSk.
__global__ __launch_bounds__(256) void gemm_tile(const unsigned short* __restrict__ A,
                                                 const unsigned short* __restrict__ Bt,
                                                 unsigned short* __restrict__ outBf,
                                                 unsigned char* __restrict__ outQ,
                                                 unsigned short* __restrict__ outSk,
                                                 const float* __restrict__ biasSk,
                                                 int M, int K, int NCtot, int split,
                                                 int ldBf, int ldSk) {
    __shared__ __align__(16) char smem[2][2][8192];
    int t = threadIdx.x;
    int w = t >> 6, lane = t & 63;
    int l16 = lane & 15, quad = lane >> 4;
    int warp_r = w >> 1, warp_c = w & 1;
    int rowBase = blockIdx.y * 128;
    int colBase = blockIdx.x * 128;

    int row_l = t & 127;
    int jchunk = t >> 7;
    int arow_st = rowBase + row_l; if (arow_st >= M) arow_st = M - 1;
    int bcol_st = colBase + row_l; if (bcol_st >= NCtot) bcol_st = NCtot - 1;
    const unsigned short* aRow = A + (size_t)arow_st * K;
    const unsigned short* bRow = Bt + (size_t)bcol_st * K;

    f32x4 acc[4][4];
    #pragma unroll
    for (int i = 0; i < 4; i++)
        #pragma unroll
        for (int j = 0; j < 4; j++) acc[i][j] = (f32x4){0.f, 0.f, 0.f, 0.f};

    auto stage = [&](int buf, int k0) {
        #pragma unroll
        for (int j = 0; j < 2; j++) {
            int chunk = j * 2 + jchunk;
            gload_lds16(aRow + k0 + chunk * 8, &smem[buf][0][(size_t)j * 4096 + (size_t)t * 16]);
            gload_lds16(bRow + k0 + chunk * 8, &smem[buf][1][(size_t)j * 4096 + (size_t)t * 16]);
        }
    };

    stage(0, 0);
    __syncthreads();
    int niter = K >> 5;
    for (int it = 0; it < niter; ++it) {
        if (it + 1 < niter) stage((it + 1) & 1, (it + 1) << 5);
        const char* Ab = &smem[it & 1][0][0];
        const char* Bb = &smem[it & 1][1][0];
        bf16x8 a[4], b[4];
        #pragma unroll
        for (int i = 0; i < 4; i++)
            a[i] = *reinterpret_cast<const bf16x8*>(Ab + quad * 2048 + (warp_r * 64 + i * 16 + l16) * 16);
        #pragma unroll
        for (int j = 0; j < 4; j++)
            b[j] = *reinterpret_cast<const bf16x8*>(Bb + quad * 2048 + (warp_c * 64 + j * 16 + l16) * 16);
        #pragma unroll
        for (int i = 0; i < 4; i++)
            #pragma unroll
            for (int j = 0; j < 4; j++)
                acc[i][j] = __builtin_amdgcn_mfma_f32_16x16x32_bf16(a[i], b[j], acc[i][j], 0, 0, 0);
        __syncthreads();
    }

    #pragma unroll
    for (int i = 0; i < 4; i++) {
        #pragma unroll
        for (int r = 0; r < 4; r++) {
            int row = rowBase + warp_r * 64 + i * 16 + quad * 4 + r;
            if (row >= M) continue;
            #pragma unroll
            for (int j = 0; j < 4; j++) {
                int c = colBase + warp_c * 64 + j * 16 + l16;
                if (c >= NCtot) continue;
                float v = acc[i][j][r];
                if (c < split) {
                    outBf[(size_t)row * ldBf + c] = f2bf(v);
                    if (outQ) outQ[(size_t)row * ldBf + c] = f8enc(v);
                } else {
                    outSk[(size_t)row * ldSk + (c - split)] = f2bf(v + biasSk[c - split]);
                }
            }
        }
    }
}

// ---------------------------------------------------------------- alpha (H=8,C=32), wave/node
__global__ __launch_bounds__(256) void alpha256(const unsigned short* __restrict__ h,
                                                const float* __restrict__ a_s,
                                                const float* __restrict__ a_d,
                                                float* __restrict__ as_out,
                                                float* __restrict__ ad_out, int N) {
    int t = threadIdx.x;
    int n = blockIdx.x * 4 + (t >> 6);
    if (n >= N) return;
    int lane = t & 63, lane4 = lane * 4;
    ushort4 hv = *reinterpret_cast<const ushort4*>(&h[(size_t)n * 256 + lane4]);
    float4 sv = *reinterpret_cast<const float4*>(&a_s[lane4]);
    float4 dv = *reinterpret_cast<const float4*>(&a_d[lane4]);
    float h0 = bf2f(hv.x), h1 = bf2f(hv.y), h2 = bf2f(hv.z), h3 = bf2f(hv.w);
    float va = h0 * sv.x + h1 * sv.y + h2 * sv.z + h3 * sv.w;
    float vd = h0 * dv.x + h1 * dv.y + h2 * dv.z + h3 * dv.w;
    #pragma unroll
    for (int off = 1; off < 8; off <<= 1) {
        va += __shfl_xor(va, off);
        vd += __shfl_xor(vd, off);
    }
    if ((lane & 7) == 0) {
        as_out[n * 8 + (lane >> 3)] = va;
        ad_out[n * 8 + (lane >> 3)] = vd;
    }
}

// ---------------------------------------------------------------- alpha (H=1,C=32), 8 nodes/wave
__global__ __launch_bounds__(256) void alpha32(const unsigned short* __restrict__ h,
                                               const float* __restrict__ a_s,
                                               const float* __restrict__ a_d,
                                               float* __restrict__ as_out,
                                               float* __restrict__ ad_out, int N) {
    int t = threadIdx.x;
    int lane = t & 63;
    int n = blockIdx.x * 32 + (t >> 6) * 8 + (lane >> 3);
    int c4 = (lane & 7) * 4;
    if (n >= N) return;
    ushort4 hv = *reinterpret_cast<const ushort4*>(&h[(size_t)n * 32 + c4]);
    float4 sv = *reinterpret_cast<const float4*>(&a_s[c4]);
    float4 dv = *reinterpret_cast<const float4*>(&a_d[c4]);
    float h0 = bf2f(hv.x), h1 = bf2f(hv.y), h2 = bf2f(hv.z), h3 = bf2f(hv.w);
    float va = h0 * sv.x + h1 * sv.y + h2 * sv.z + h3 * sv.w;
    float vd = h0 * dv.x + h1 * dv.y + h2 * dv.z + h3 * dv.w;
    #pragma unroll
    for (int off = 1; off < 8; off <<= 1) {
        va += __shfl_xor(va, off);
        vd += __shfl_xor(vd, off);
    }
    if ((lane & 7) == 0) {
        as_out[n] = va;
        ad_out[n] = vd;
    }
}

// ---------------------------------------------------------------- aggregation H=8,C=32
// R8 structure (one wave/node, single pass, pipelined weight chain),
// gathering the fp8 copy: 256B/row instead of 512B -> halves L2-miss demand.
template <int MODE>
__global__ __launch_bounds__(256) void agg256(const unsigned char* __restrict__ hq,
                                              const float* __restrict__ as,
                                              const float* __restrict__ ad,
                                              const int* __restrict__ indptr,
                                              const int* __restrict__ esrc,
                                              const float* __restrict__ bias,
                                              const float* __restrict__ bn_g,
                                              const float* __restrict__ bn_b,
                                              const float* __restrict__ bn_m,
                                              const float* __restrict__ bn_v,
                                              const unsigned short* __restrict__ skip,
                                              unsigned short* __restrict__ out, int N) {
    int t = threadIdx.x;
    int n = blockIdx.x * 4 + (t >> 6);
    if (n >= N) return;
    int lane = t & 63;
    int e_sub = lane >> 3, h_sub = lane & 7;
    int ch_head = lane >> 3;
    int lane4 = lane * 4;
    int start = indptr[n], end = indptr[n + 1];
    int cnt = end - start;

    float adh = ad[n * 8 + h_sub];

    float4 acc = make_float4(0.f, 0.f, 0.f, 0.f);
    float sm = 0.f;
    int nfull = cnt & ~7;
    int i0 = start;
    int s_l = 0; float w8 = 0.f;
    if (nfull) {
        s_l = esrc[i0 + e_sub];
        w8 = __expf(lrelu(as[s_l * 8 + h_sub] + adh));
    }
    while (i0 < start + nfull) {
        int s_cur = s_l;
        float w_cur = w8;
        i0 += 8;
        if (i0 < start + nfull) {
            s_l = esrc[i0 + e_sub];
            w8 = __expf(lrelu(as[s_l * 8 + h_sub] + adh));
        }
        sm += w_cur;
        unsigned int hv[8];
        #pragma unroll
        for (int e = 0; e < 8; e++) {
            int se = __shfl(s_cur, e * 8);
            hv[e] = *reinterpret_cast<const unsigned int*>(&hq[(size_t)se * 256 + lane4]);
        }
        #pragma unroll
        for (int e = 0; e < 8; e++) {
            float we = __shfl(w_cur, e * 8 + ch_head);
            acc.x = fmaf(we, f8dec<0>(hv[e]), acc.x);
            acc.y = fmaf(we, f8dec<1>(hv[e]), acc.y);
            acc.z = fmaf(we, f8dec<2>(hv[e]), acc.z);
            acc.w = fmaf(we, f8dec<3>(hv[e]), acc.w);
        }
    }
    int rem = cnt - nfull;
    if (rem) {
        int idx = i0 + e_sub;
        int s_r = esrc[idx < end ? idx : end - 1];
        float w_r = (idx < end) ? __expf(lrelu(as[s_r * 8 + h_sub] + adh)) : 0.f;
        sm += w_r;
        #pragma unroll
        for (int e = 0; e < 8; e++) {
            if (e < rem) {
                int se = __shfl(s_r, e * 8);
                float we = __shfl(w_r, e * 8 + ch_head);
                unsigned int hv = *reinterpret_cast<const unsigned int*>(&hq[(size_t)se * 256 + lane4]);
                acc.x = fmaf(we, f8dec<0>(hv), acc.x);
                acc.y = fmaf(we, f8dec<1>(hv), acc.y);
                acc.z = fmaf(we, f8dec<2>(hv), acc.z);
                acc.w = fmaf(we, f8dec<3>(hv), acc.w);
            }
        }
    }
    #pragma unroll
    for (int off = 8; off < 64; off <<= 1) sm += __shfl_xor(sm, off);
    float il = 1.f / (sm + 1e-16f);
    float il_c = __shfl(il, ch_head);

    float4 bv  = *reinterpret_cast<const float4*>(&bias[lane4]);
    float4 gv  = *reinterpret_cast<const float4*>(&bn_g[lane4]);
    float4 bbv = *reinterpret_cast<const float4*>(&bn_b[lane4]);
    float4 mv  = *reinterpret_cast<const float4*>(&bn_m[lane4]);
    float4 vv  = *reinterpret_cast<const float4*>(&bn_v[lane4]);
    float o[4] = {acc.x * il_c + bv.x, acc.y * il_c + bv.y,
                  acc.z * il_c + bv.z, acc.w * il_c + bv.w};
    float g[4] = {gv.x, gv.y, gv.z, gv.w}, bb[4] = {bbv.x, bbv.y, bbv.z, bbv.w};
    float m[4] = {mv.x, mv.y, mv.z, mv.w}, vr[4] = {vv.x, vv.y, vv.z, vv.w};
    float sk[4] = {0.f, 0.f, 0.f, 0.f};
    if (MODE == 1) {
        ushort4 s4 = *reinterpret_cast<const ushort4*>(&skip[(size_t)n * 256 + lane4]);
        sk[0] = bf2f(s4.x); sk[1] = bf2f(s4.y); sk[2] = bf2f(s4.z); sk[3] = bf2f(s4.w);
    }
    ushort4 res;
    unsigned short* rp = &res.x;
    #pragma unroll
    for (int j = 0; j < 4; j++) {
        float val = (o[j] - m[j]) * rsqrtf(vr[j] + BN_EPS) * g[j] + bb[j];
        val = val > 0.f ? val : (__expf(val) - 1.f);
        val += sk[j];
        rp[j] = f2bf(val);
    }
    *reinterpret_cast<ushort4*>(&out[(size_t)n * 256 + lane4]) = res;
}

// ---------------------------------------------------------------- aggregation H=1,C=32
__global__ __launch_bounds__(256) void agg32(const unsigned short* __restrict__ h3,
                                             const float* __restrict__ as,
                                             const float* __restrict__ ad,
                                             const int* __restrict__ indptr,
                                             const int* __restrict__ esrc,
                                             const float* __restrict__ b3,
                                             const unsigned short* __restrict__ xs,
                                             float* __restrict__ out, int N) {
    int t = threadIdx.x;
    int n = blockIdx.x * 4 + (t >> 6);
    if (n >= N) return;
    int lane = t & 63;
    int e_sub = lane >> 3, c4 = (lane & 7) * 4;
    int start = indptr[n], end = indptr[n + 1];
    float adn = ad[n];

    float4 acc = make_float4(0.f, 0.f, 0.f, 0.f);
    float sm = 0.f;
    int i0 = start;
    for (; i0 + 16 <= end; i0 += 16) {
        int sA = esrc[i0 + e_sub];
        int sB = esrc[i0 + 8 + e_sub];
        float wA = __expf(lrelu(as[sA] + adn));
        float wB = __expf(lrelu(as[sB] + adn));
        sm += wA + wB;
        ushort4 hA = *reinterpret_cast<const ushort4*>(&h3[(size_t)sA * 32 + c4]);
        ushort4 hB = *reinterpret_cast<const ushort4*>(&h3[(size_t)sB * 32 + c4]);
        acc.x = fmaf(wA, bf2f(hA.x), acc.x); acc.y = fmaf(wA, bf2f(hA.y), acc.y);
        acc.z = fmaf(wA, bf2f(hA.z), acc.z); acc.w = fmaf(wA, bf2f(hA.w), acc.w);
        acc.x = fmaf(wB, bf2f(hB.x), acc.x); acc.y = fmaf(wB, bf2f(hB.y), acc.y);
        acc.z = fmaf(wB, bf2f(hB.z), acc.z); acc.w = fmaf(wB, bf2f(hB.w), acc.w);
    }
    for (; i0 < end; i0 += 8) {
        int idx = i0 + e_sub;
        bool valid = idx < end;
        if (valid) {
            int s = esrc[idx];
            float w = __expf(lrelu(as[s] + adn));
            sm += w;
            ushort4 hv = *reinterpret_cast<const ushort4*>(&h3[(size_t)s * 32 + c4]);
            acc.x = fmaf(w, bf2f(hv.x), acc.x);
            acc.y = fmaf(w, bf2f(hv.y), acc.y);
            acc.z = fmaf(w, bf2f(hv.z), acc.z);
            acc.w = fmaf(w, bf2f(hv.w), acc.w);
        }
    }
    #pragma unroll
    for (int off = 8; off < 64; off <<= 1) {
        sm    += __shfl_xor(sm, off);
        acc.x += __shfl_xor(acc.x, off);
        acc.y += __shfl_xor(acc.y, off);
        acc.z += __shfl_xor(acc.z, off);
        acc.w += __shfl_xor(acc.w, off);
    }
    if (e_sub == 0) {
        float il = 1.f / (sm + 1e-16f);
        float4 bv = *reinterpret_cast<const float4*>(&b3[c4]);
        ushort4 xv = *reinterpret_cast<const ushort4*>(&xs[(size_t)n * 32 + c4]);
        float4 o;
        o.x = acc.x * il + bv.x + bf2f(xv.x);
        o.y = acc.y * il + bv.y + bf2f(xv.y);
        o.z = acc.z * il + bv.z + bf2f(xv.z);
        o.w = acc.w * il + bv.w + bf2f(xv.w);
        *reinterpret_cast<float4*>(&out[(size_t)n * 32 + c4]) = o;
    }
}

// ---------------------------------------------------------------- launch
extern "C" void kernel_launch(void* const* d_in, const int* in_sizes, int n_in,
                              void* d_out, int out_size, void* d_ws, size_t ws_size,
                              hipStream_t stream) {
    const float* x      = (const float*)d_in[0];
    const int*   eidx   = (const int*)  d_in[1];
    const float* W1     = (const float*)d_in[2];
    const float* a_src1 = (const float*)d_in[3];
    const float* a_dst1 = (const float*)d_in[4];
    const float* b1     = (const float*)d_in[5];
    const float* bn1_g  = (const float*)d_in[6];
    const float* bn1_b  = (const float*)d_in[7];
    const float* bn1_m  = (const float*)d_in[8];
    const float* bn1_v  = (const float*)d_in[9];
    const float* W2     = (const float*)d_in[10];
    const float* a_src2 = (const float*)d_in[11];
    const float* a_dst2 = (const float*)d_in[12];
    const float* b2     = (const float*)d_in[13];
    const float* bn2_g  = (const float*)d_in[14];
    const float* bn2_b  = (const float*)d_in[15];
    const float* bn2_m  = (const float*)d_in[16];
    const float* bn2_v  = (const float*)d_in[17];
    const float* W3     = (const float*)d_in[18];
    const float* a_src3 = (const float*)d_in[19];
    const float* a_dst3 = (const float*)d_in[20];
    const float* b3     = (const float*)d_in[21];
    const float* Ws1    = (const float*)d_in[22];
    const float* bs1    = (const float*)d_in[23];
    const float* Ws2    = (const float*)d_in[24];
    const float* bs2    = (const float*)d_in[25];

    const int N = in_sizes[0] / 128;   // 50000
    const int E = in_sizes[1] / 2;     // 800000
    const int Etot = E + N;
    const int* srcl = eidx;
    const int* dstl = eidx + E;

    char* ws = (char*)d_ws;
    size_t off = 0;
    auto alloc = [&](size_t bytes) -> void* {
        void* p = ws + off;
        off += (bytes + 255) & ~(size_t)255;
        return p;
    };
    unsigned short* xb    = (unsigned short*)alloc((size_t)N * 128 * 2);
    unsigned short* feat  = (unsigned short*)alloc((size_t)N * 256 * 2); // x0 skip (bf16)
    unsigned short* hbuf  = (unsigned short*)alloc((size_t)N * 256 * 2); // gemm h output (bf16)
    unsigned char*  hq    = (unsigned char*)alloc((size_t)N * 256);     // fp8 copy for gathers
    unsigned short* h2b   = (unsigned short*)alloc((size_t)N * 256 * 2); // layer-1 agg out
    unsigned short* featb = (unsigned short*)alloc((size_t)N * 256 * 2); // layer-2 agg out
    unsigned short* xsbuf = (unsigned short*)alloc((size_t)N * 32 * 2);  // xs skip (bf16)
    unsigned short* h3b   = (unsigned short*)alloc((size_t)N * 32 * 2);
    float*          asb   = (float*)alloc((size_t)N * 8 * 4);
    float*          adb   = (float*)alloc((size_t)N * 8 * 4);
    unsigned short* Wcat1 = (unsigned short*)alloc((size_t)512 * 128 * 2); // [W1t; Ws1t]
    unsigned short* Wcat2 = (unsigned short*)alloc((size_t)288 * 256 * 2); // [W2t; Ws2t]
    unsigned short* W3t   = (unsigned short*)alloc((size_t)32 * 256 * 2);
    int* counts = (int*)alloc((size_t)N * 4);
    int* cursor = (int*)alloc((size_t)N * 4);
    int* indptr = (int*)alloc((size_t)(N + 1) * 4);
    int* bsums  = (int*)alloc(256 * 4);
    int* esrc   = (int*)alloc((size_t)Etot * 4);
    (void)ws_size; (void)n_in; (void)out_size;

    // ---- CSR by dst
    hipMemsetAsync(counts, 0, (size_t)N * 4, stream);
    int ceb = (Etot + 255) / 256;
    int nb  = (N + 255) / 256;
    count_kernel<<<ceb, 256, 0, stream>>>(dstl, E, N, counts);
    scan1<<<nb, 256, 0, stream>>>(counts, cursor, bsums, N);
    scan2<<<1, 256, 0, stream>>>(bsums, nb);
    scan3<<<nb, 256, 0, stream>>>(cursor, bsums, counts, indptr, cursor, N);
    fill_kernel<<<ceb, 256, 0, stream>>>(srcl, dstl, E, N, cursor, esrc);

    // ---- convert inputs (x -> bf16, weights -> transposed bf16) in one dispatch
    int n4x = N * 128 / 4;
    prep_all<<<(n4x + 147456 + 255) / 256, 256, 0, stream>>>(x, xb, n4x,
                                                             W1, Ws1, W2, Ws2, W3,
                                                             Wcat1, Wcat2, W3t);

    int gy128 = (N + 127) / 128;
    int gn4 = (N + 3) / 4;

    // ---- layer 1: fused [h1 | x0] = x @ [W1 | Ws1]  (+ fp8 copy of h1)
    gemm_tile<<<dim3(4, gy128), 256, 0, stream>>>(xb, Wcat1, hbuf, hq, feat, bs1,
                                                  N, 128, 512, 256, 256, 256);
    alpha256<<<gn4, 256, 0, stream>>>(hbuf, a_src1, a_dst1, asb, adb, N);
    agg256<1><<<gn4, 256, 0, stream>>>(hq, asb, adb, indptr, esrc, b1,
                                       bn1_g, bn1_b, bn1_m, bn1_v, feat, h2b, N);

    // ---- layer 2: fused [h2 | xs] = h @ [W2 | Ws2]  (+ fp8 copy of h2)
    gemm_tile<<<dim3(3, gy128), 256, 0, stream>>>(h2b, Wcat2, hbuf, hq, xsbuf, bs2,
                                                  N, 256, 288, 256, 256, 32);
    alpha256<<<gn4, 256, 0, stream>>>(hbuf, a_src2, a_dst2, asb, adb, N);
    agg256<0><<<gn4, 256, 0, stream>>>(hq, asb, adb, indptr, esrc, b2,
                                       bn2_g, bn2_b, bn2_m, bn2_v, nullptr, featb, N);

    // ---- layer 3: tiled GEMM (NCtot=32)
    gemm_tile<<<dim3(1, gy128), 256, 0, stream>>>(featb, W3t, h3b, nullptr, h3b, nullptr,
                                                  N, 256, 32, 32, 32, 32);
    alpha32<<<(N + 31) / 32, 256, 0, stream>>>(h3b, a_src3, a_dst3, asb, adb, N);
    agg32<<<gn4, 256, 0, stream>>>(h3b, asb, adb, indptr, esrc, b3, xsbuf,
                                   (float*)d_out, N);
}

// Round 11
// 411.123 us; speedup vs baseline: 1.2630x; 1.1264x over previous
//
#include <hip/hip_runtime.h>
#include <hip/hip_bf16.h>

#define NEG_SLOPE 0.2f
#define BN_EPS 1e-5f
#define BSH 8              // bucket shift: 256 nodes per bucket
#define STASH_CAP 6400     // K4 LDS stash entries (mean ~4600, +27 sigma)

typedef __attribute__((ext_vector_type(8))) short bf16x8;
typedef __attribute__((ext_vector_type(4))) float f32x4;

#if defined(__has_builtin)
#if __has_builtin(__builtin_amdgcn_cvt_f32_fp8) && __has_builtin(__builtin_amdgcn_cvt_pk_fp8_f32)
#define HW_FP8 1
#endif
#endif

__device__ __forceinline__ float bf2f(unsigned short u) {
    union { unsigned int i; float f; } x;
    x.i = ((unsigned int)u) << 16;
    return x.f;
}
__device__ __forceinline__ unsigned short f2bf(float f) {
    __hip_bfloat16 b = __float2bfloat16(f);
    return *reinterpret_cast<unsigned short*>(&b);
}
__device__ __forceinline__ float lrelu(float v) {
    return v > 0.f ? v : NEG_SLOPE * v;
}
__device__ __forceinline__ void gload_lds16(const void* g, void* l) {
    __builtin_amdgcn_global_load_lds(
        (const __attribute__((address_space(1))) unsigned int*)(g),
        (__attribute__((address_space(3))) unsigned int*)(l),
        16, 0, 0);
}

// ---- fp8 e4m3 (OCP) encode/decode: HW path + software fallback
__device__ __forceinline__ unsigned char f8enc(float f) {
#ifdef HW_FP8
    int p = __builtin_amdgcn_cvt_pk_fp8_f32(f, 0.f, 0, false);
    return (unsigned char)(p & 0xff);
#else
    float a = fabsf(f);
    unsigned int sign = (__float_as_uint(f) >> 31) << 7;
    if (a < 0.0009765625f) return (unsigned char)sign;
    a = fminf(a, 448.f);
    unsigned int bits = __float_as_uint(a);
    int e = (int)((bits >> 23) & 0xff) - 127;
    unsigned int mant = bits & 0x7fffff;
    if (e < -6) {
        int q = (int)(a * 512.f + 0.5f);
        if (q >= 8) return (unsigned char)(sign | 0x08);
        return (unsigned char)(sign | q);
    }
    unsigned int m = mant >> 20;
    unsigned int rem = mant & 0xfffff;
    if (rem > 0x80000 || (rem == 0x80000 && (m & 1))) m++;
    if (m == 8) { m = 0; e++; }
    if (e > 8) { e = 8; m = 6; }
    return (unsigned char)(sign | ((unsigned int)(e + 7) << 3) | m);
#endif
}
template <int SEL>
__device__ __forceinline__ float f8dec(unsigned int w) {
#ifdef HW_FP8
    return __builtin_amdgcn_cvt_f32_fp8(w, SEL);
#else
    unsigned int b = (w >> (SEL * 8)) & 0xff;
    unsigned int s = b >> 7, em = b & 0x7f;
    float mag;
    if (em >= 8) {
        unsigned int bits = (((em >> 3) + 120) << 23) | ((em & 7) << 20);
        mag = __uint_as_float(bits);
    } else {
        mag = (float)em * 0.001953125f;
    }
    return s ? -mag : mag;
#endif
}

__device__ __forceinline__ int block_scan_incl(int v, int t) {
    int lane = t & 63, w = t >> 6;
    int sv = v;
    #pragma unroll
    for (int off = 1; off < 64; off <<= 1) {
        int u = __shfl_up(sv, off);
        if (lane >= off) sv += u;
    }
    __shared__ int ws_[4];
    if (lane == 63) ws_[w] = sv;
    __syncthreads();
    if (t == 0) {
        int a = 0;
        #pragma unroll
        for (int k = 0; k < 4; k++) { int x = ws_[k]; ws_[k] = a; a += x; }
    }
    __syncthreads();
    return sv + ws_[w];
}

// ================================================================ CSR build (bucketed multi-split)
// K1: global bucket histogram (LDS-staged)
__global__ __launch_bounds__(256) void bucket_count(const int* __restrict__ dstl,
                                                    int E, int N, int NB,
                                                    int* __restrict__ gHist) {
    __shared__ int h[256];
    int t = threadIdx.x;
    h[t] = 0;
    __syncthreads();
    int Etot = E + N;
    for (int i = blockIdx.x * 256 + t; i < Etot; i += gridDim.x * 256) {
        int d = (i < E) ? dstl[i] : (i - E);
        atomicAdd(&h[d >> BSH], 1);
    }
    __syncthreads();
    if (t < NB && h[t]) atomicAdd(&gHist[t], h[t]);
}

// K2: scan bucket counts -> bases + cursor init (1 block)
__global__ __launch_bounds__(256) void bucket_scan(const int* __restrict__ gHist,
                                                   int* __restrict__ bases,
                                                   int* __restrict__ gCursor, int NB) {
    int t = threadIdx.x;
    int v = (t < NB) ? gHist[t] : 0;
    int incl = block_scan_incl(v, t);
    if (t < NB) { bases[t] = incl - v; gCursor[t] = incl - v; }
}

// K3: scatter packed (src<<8 | dstLow) into bucket regions, LDS-staged for
// line-dense global writes. Barrier-only (no spinlocks). 4096 edges/block.
__global__ __launch_bounds__(256) void bucket_scatter(const int* __restrict__ srcl,
                                                      const int* __restrict__ dstl,
                                                      int E, int N, int NB,
                                                      int* __restrict__ gCursor,
                                                      unsigned int* __restrict__ bktEdges) {
    __shared__ unsigned int stage[4096];
    __shared__ int hist[256];
    __shared__ int bexcl[257];
    __shared__ int curk[256];
    __shared__ int gbase[256];
    int t = threadIdx.x;
    int Etot = E + N;
    int begin = blockIdx.x * 4096;

    hist[t] = 0;
    __syncthreads();

    unsigned int ent[16];
    int eb[16];
    #pragma unroll
    for (int k = 0; k < 16; k++) {
        int i = begin + k * 256 + t;
        if (i < Etot) {
            int s, d;
            if (i < E) { s = srcl[i]; d = dstl[i]; }
            else       { s = d = i - E; }
            eb[k] = d >> BSH;
            ent[k] = ((unsigned int)s << BSH) | (unsigned int)(d & 255);
            atomicAdd(&hist[eb[k]], 1);
        } else eb[k] = -1;
    }
    __syncthreads();

    int v = hist[t];                       // 0 for t >= NB
    int incl = block_scan_incl(v, t);      // block-wide, all threads participate
    bexcl[t] = incl - v;
    curk[t] = incl - v;
    if (t == 255) bexcl[256] = incl;       // total entries this block
    __syncthreads();

    #pragma unroll
    for (int k = 0; k < 16; k++) {
        if (eb[k] >= 0) {
            int slot = atomicAdd(&curk[eb[k]], 1);
            stage[slot] = ent[k];
        }
    }
    if (t < NB) {
        int cnt = hist[t];
        gbase[t] = cnt ? atomicAdd(&gCursor[t], cnt) : 0;
    }
    __syncthreads();

    int total = bexcl[256];
    for (int p = t; p < total; p += 256) {
        // find bucket b: largest b with bexcl[b] <= p
        int lo = 0, hi = NB - 1;
        while (lo < hi) {
            int mid = (lo + hi + 1) >> 1;
            if (bexcl[mid] <= p) lo = mid; else hi = mid - 1;
        }
        bktEdges[gbase[lo] + (p - bexcl[lo])] = stage[p];
    }
}

// K4: per-bucket -> fine CSR. One block per bucket; per-node LDS hist+scan
// writes indptr and scatters esrc within a single-XCD-local window.
__global__ __launch_bounds__(256) void bucket_to_csr(const unsigned int* __restrict__ bktEdges,
                                                     const int* __restrict__ bases,
                                                     const int* __restrict__ gCursor,
                                                     int* __restrict__ indptr,
                                                     int* __restrict__ esrc,
                                                     int N, int NB, int Etot) {
    __shared__ int nh[256];
    __shared__ int ncur[256];
    __shared__ unsigned int stash[STASH_CAP];
    int b = blockIdx.x, t = threadIdx.x;
    int base = bases[b];
    int cnt = gCursor[b] - base;           // gCursor after K3 == base + count
    int nodeBase = b << BSH;

    nh[t] = 0;
    __syncthreads();
    for (int p = t; p < cnt; p += 256) {
        unsigned int e = bktEdges[base + p];
        if (p < STASH_CAP) stash[p] = e;
        atomicAdd(&nh[e & 255], 1);
    }
    __syncthreads();
    int v = nh[t];
    int incl = block_scan_incl(v, t);
    int excl = incl - v;
    ncur[t] = excl;
    if (nodeBase + t < N) indptr[nodeBase + t] = base + excl;
    __syncthreads();
    for (int p = t; p < cnt; p += 256) {
        unsigned int e = (p < STASH_CAP) ? stash[p] : bktEdges[base + p];
        int slot = atomicAdd(&ncur[e & 255], 1);
        esrc[base + slot] = (int)(e >> BSH);
    }
    if (b == 0 && t == 0) indptr[N] = Etot;
}

// ---------------------------------------------------------------- prep: x->bf16 + all weight transposes
__global__ __launch_bounds__(256) void prep_all(const float* __restrict__ x,
                                                unsigned short* __restrict__ xb, int n4x,
                                                const float* __restrict__ W1,
                                                const float* __restrict__ Ws1,
                                                const float* __restrict__ W2,
                                                const float* __restrict__ Ws2,
                                                const float* __restrict__ W3,
                                                unsigned short* __restrict__ Wcat1,
                                                unsigned short* __restrict__ Wcat2,
                                                unsigned short* __restrict__ W3t) {
    int i = blockIdx.x * 256 + threadIdx.x;
    if (i < n4x) {
        float4 v = reinterpret_cast<const float4*>(x)[i];
        ushort4 o;
        o.x = f2bf(v.x); o.y = f2bf(v.y); o.z = f2bf(v.z); o.w = f2bf(v.w);
        reinterpret_cast<ushort4*>(xb)[i] = o;
        return;
    }
    int j = i - n4x;
    if (j < 32768) {
        int m = j >> 7, k = j & 127;
        Wcat1[j] = f2bf(W1[k * 256 + m]);
    } else if (j < 65536) {
        int q = j - 32768; int m = q >> 7, k = q & 127;
        Wcat1[32768 + q] = f2bf(Ws1[k * 256 + m]);
    } else if (j < 131072) {
        int q = j - 65536; int m = q >> 8, k = q & 255;
        Wcat2[q] = f2bf(W2[k * 256 + m]);
    } else if (j < 139264) {
        int q = j - 131072; int m = q >> 8, k = q & 255;
        Wcat2[65536 + q] = f2bf(Ws2[k * 32 + m]);
    } else if (j < 147456) {
        int q = j - 139264; int m = q >> 8, k = q & 255;
        W3t[q] = f2bf(W3[k * 32 + m]);
    }
}

// ---------------------------------------------------------------- tiled MFMA GEMM
__global__ __launch_bounds__(256) void gemm_tile(const unsigned short* __restrict__ A,
                                                 const unsigned short* __restrict__ Bt,
                                                 unsigned short* __restrict__ outBf,
                                                 unsigned char* __restrict__ outQ,
                                                 unsigned short* __restrict__ outSk,
                                                 const float* __restrict__ biasSk,
                                                 int M, int K, int NCtot, int split,
                                                 int ldBf, int ldSk) {
    __shared__ __align__(16) char smem[2][2][8192];
    int t = threadIdx.x;
    int w = t >> 6, lane = t & 63;
    int l16 = lane & 15, quad = lane >> 4;
    int warp_r = w >> 1, warp_c = w & 1;
    int rowBase = blockIdx.y * 128;
    int colBase = blockIdx.x * 128;

    int row_l = t & 127;
    int jchunk = t >> 7;
    int arow_st = rowBase + row_l; if (arow_st >= M) arow_st = M - 1;
    int bcol_st = colBase + row_l; if (bcol_st >= NCtot) bcol_st = NCtot - 1;
    const unsigned short* aRow = A + (size_t)arow_st * K;
    const unsigned short* bRow = Bt + (size_t)bcol_st * K;

    f32x4 acc[4][4];
    #pragma unroll
    for (int i = 0; i < 4; i++)
        #pragma unroll
        for (int j = 0; j < 4; j++) acc[i][j] = (f32x4){0.f, 0.f, 0.f, 0.f};

    auto stage = [&](int buf, int k0) {
        #pragma unroll
        for (int j = 0; j < 2; j++) {
            int chunk = j * 2 + jchunk;
            gload_lds16(aRow + k0 + chunk * 8, &smem[buf][0][(size_t)j * 4096 + (size_t)t * 16]);
            gload_lds16(bRow + k0 + chunk * 8, &smem[buf][1][(size_t)j * 4096 + (size_t)t * 16]);
        }
    };

    stage(0, 0);
    __syncthreads();
    int niter = K >> 5;
    for (int it = 0; it < niter; ++it) {
        if (it + 1 < niter) stage((it + 1) & 1, (it + 1) << 5);
        const char* Ab = &smem[it & 1][0][0];
        const char* Bb = &smem[it & 1][1][0];
        bf16x8 a[4], b[4];
        #pragma unroll
        for (int i = 0; i < 4; i++)
            a[i] = *reinterpret_cast<const bf16x8*>(Ab + quad * 2048 + (warp_r * 64 + i * 16 + l16) * 16);
        #pragma unroll
        for (int j = 0; j < 4; j++)
            b[j] = *reinterpret_cast<const bf16x8*>(Bb + quad * 2048 + (warp_c * 64 + j * 16 + l16) * 16);
        #pragma unroll
        for (int i = 0; i < 4; i++)
            #pragma unroll
            for (int j = 0; j < 4; j++)
                acc[i][j] = __builtin_amdgcn_mfma_f32_16x16x32_bf16(a[i], b[j], acc[i][j], 0, 0, 0);
        __syncthreads();
    }

    #pragma unroll
    for (int i = 0; i < 4; i++) {
        #pragma unroll
        for (int r = 0; r < 4; r++) {
            int row = rowBase + warp_r * 64 + i * 16 + quad * 4 + r;
            if (row >= M) continue;
            #pragma unroll
            for (int j = 0; j < 4; j++) {
                int c = colBase + warp_c * 64 + j * 16 + l16;
                if (c >= NCtot) continue;
                float v = acc[i][j][r];
                if (c < split) {
                    outBf[(size_t)row * ldBf + c] = f2bf(v);
                    if (outQ) outQ[(size_t)row * ldBf + c] = f8enc(v);
                } else {
                    outSk[(size_t)row * ldSk + (c - split)] = f2bf(v + biasSk[c - split]);
                }
            }
        }
    }
}

// ---------------------------------------------------------------- alpha (H=8,C=32), wave/node
__global__ __launch_bounds__(256) void alpha256(const unsigned short* __restrict__ h,
                                                const float* __restrict__ a_s,
                                                const float* __restrict__ a_d,
                                                float* __restrict__ as_out,
                                                float* __restrict__ ad_out, int N) {
    int t = threadIdx.x;
    int n = blockIdx.x * 4 + (t >> 6);
    if (n >= N) return;
    int lane = t & 63, lane4 = lane * 4;
    ushort4 hv = *reinterpret_cast<const ushort4*>(&h[(size_t)n * 256 + lane4]);
    float4 sv = *reinterpret_cast<const float4*>(&a_s[lane4]);
    float4 dv = *reinterpret_cast<const float4*>(&a_d[lane4]);
    float h0 = bf2f(hv.x), h1 = bf2f(hv.y), h2 = bf2f(hv.z), h3 = bf2f(hv.w);
    float va = h0 * sv.x + h1 * sv.y + h2 * sv.z + h3 * sv.w;
    float vd = h0 * dv.x + h1 * dv.y + h2 * dv.z + h3 * dv.w;
    #pragma unroll
    for (int off = 1; off < 8; off <<= 1) {
        va += __shfl_xor(va, off);
        vd += __shfl_xor(vd, off);
    }
    if ((lane & 7) == 0) {
        as_out[n * 8 + (lane >> 3)] = va;
        ad_out[n * 8 + (lane >> 3)] = vd;
    }
}

// ---------------------------------------------------------------- alpha (H=1,C=32), 8 nodes/wave
__global__ __launch_bounds__(256) void alpha32(const unsigned short* __restrict__ h,
                                               const float* __restrict__ a_s,
                                               const float* __restrict__ a_d,
                                               float* __restrict__ as_out,
                                               float* __restrict__ ad_out, int N) {
    int t = threadIdx.x;
    int lane = t & 63;
    int n = blockIdx.x * 32 + (t >> 6) * 8 + (lane >> 3);
    int c4 = (lane & 7) * 4;
    if (n >= N) return;
    ushort4 hv = *reinterpret_cast<const ushort4*>(&h[(size_t)n * 32 + c4]);
    float4 sv = *reinterpret_cast<const float4*>(&a_s[c4]);
    float4 dv = *reinterpret_cast<const float4*>(&a_d[c4]);
    float h0 = bf2f(hv.x), h1 = bf2f(hv.y), h2 = bf2f(hv.z), h3 = bf2f(hv.w);
    float va = h0 * sv.x + h1 * sv.y + h2 * sv.z + h3 * sv.w;
    float vd = h0 * dv.x + h1 * dv.y + h2 * dv.z + h3 * dv.w;
    #pragma unroll
    for (int off = 1; off < 8; off <<= 1) {
        va += __shfl_xor(va, off);
        vd += __shfl_xor(vd, off);
    }
    if ((lane & 7) == 0) {
        as_out[n] = va;
        ad_out[n] = vd;
    }
}

// ---------------------------------------------------------------- aggregation H=8,C=32 (fp8 gather)
template <int MODE>
__global__ __launch_bounds__(256) void agg256(const unsigned char* __restrict__ hq,
                                              const float* __restrict__ as,
                                              const float* __restrict__ ad,
                                              const int* __restrict__ indptr,
                                              const int* __restrict__ esrc,
                                              const float* __restrict__ bias,
                                              const float* __restrict__ bn_g,
                                              const float* __restrict__ bn_b,
                                              const float* __restrict__ bn_m,
                                              const float* __restrict__ bn_v,
                                              const unsigned short* __restrict__ skip,
                                              unsigned short* __restrict__ out, int N) {
    int t = threadIdx.x;
    int n = blockIdx.x * 4 + (t >> 6);
    if (n >= N) return;
    int lane = t & 63;
    int e_sub = lane >> 3, h_sub = lane & 7;
    int ch_head = lane >> 3;
    int lane4 = lane * 4;
    int start = indptr[n], end = indptr[n + 1];
    int cnt = end - start;

    float adh = ad[n * 8 + h_sub];

    float4 acc = make_float4(0.f, 0.f, 0.f, 0.f);
    float sm = 0.f;
    int nfull = cnt & ~7;
    int i0 = start;
    int s_l = 0; float w8 = 0.f;
    if (nfull) {
        s_l = esrc[i0 + e_sub];
        w8 = __expf(lrelu(as[s_l * 8 + h_sub] + adh));
    }
    while (i0 < start + nfull) {
        int s_cur = s_l;
        float w_cur = w8;
        i0 += 8;
        if (i0 < start + nfull) {
            s_l = esrc[i0 + e_sub];
            w8 = __expf(lrelu(as[s_l * 8 + h_sub] + adh));
        }
        sm += w_cur;
        unsigned int hv[8];
        #pragma unroll
        for (int e = 0; e < 8; e++) {
            int se = __shfl(s_cur, e * 8);
            hv[e] = *reinterpret_cast<const unsigned int*>(&hq[(size_t)se * 256 + lane4]);
        }
        #pragma unroll
        for (int e = 0; e < 8; e++) {
            float we = __shfl(w_cur, e * 8 + ch_head);
            acc.x = fmaf(we, f8dec<0>(hv[e]), acc.x);
            acc.y = fmaf(we, f8dec<1>(hv[e]), acc.y);
            acc.z = fmaf(we, f8dec<2>(hv[e]), acc.z);
            acc.w = fmaf(we, f8dec<3>(hv[e]), acc.w);
        }
    }
    int rem = cnt - nfull;
    if (rem) {
        int idx = i0 + e_sub;
        int s_r = esrc[idx < end ? idx : end - 1];
        float w_r = (idx < end) ? __expf(lrelu(as[s_r * 8 + h_sub] + adh)) : 0.f;
        sm += w_r;
        #pragma unroll
        for (int e = 0; e < 8; e++) {
            if (e < rem) {
                int se = __shfl(s_r, e * 8);
                float we = __shfl(w_r, e * 8 + ch_head);
                unsigned int hv = *reinterpret_cast<const unsigned int*>(&hq[(size_t)se * 256 + lane4]);
                acc.x = fmaf(we, f8dec<0>(hv), acc.x);
                acc.y = fmaf(we, f8dec<1>(hv), acc.y);
                acc.z = fmaf(we, f8dec<2>(hv), acc.z);
                acc.w = fmaf(we, f8dec<3>(hv), acc.w);
            }
        }
    }
    #pragma unroll
    for (int off = 8; off < 64; off <<= 1) sm += __shfl_xor(sm, off);
    float il = 1.f / (sm + 1e-16f);
    float il_c = __shfl(il, ch_head);

    float4 bv  = *reinterpret_cast<const float4*>(&bias[lane4]);
    float4 gv  = *reinterpret_cast<const float4*>(&bn_g[lane4]);
    float4 bbv = *reinterpret_cast<const float4*>(&bn_b[lane4]);
    float4 mv  = *reinterpret_cast<const float4*>(&bn_m[lane4]);
    float4 vv  = *reinterpret_cast<const float4*>(&bn_v[lane4]);
    float o[4] = {acc.x * il_c + bv.x, acc.y * il_c + bv.y,
                  acc.z * il_c + bv.z, acc.w * il_c + bv.w};
    float g[4] = {gv.x, gv.y, gv.z, gv.w}, bb[4] = {bbv.x, bbv.y, bbv.z, bbv.w};
    float m[4] = {mv.x, mv.y, mv.z, mv.w}, vr[4] = {vv.x, vv.y, vv.z, vv.w};
    float sk[4] = {0.f, 0.f, 0.f, 0.f};
    if (MODE == 1) {
        ushort4 s4 = *reinterpret_cast<const ushort4*>(&skip[(size_t)n * 256 + lane4]);
        sk[0] = bf2f(s4.x); sk[1] = bf2f(s4.y); sk[2] = bf2f(s4.z); sk[3] = bf2f(s4.w);
    }
    ushort4 res;
    unsigned short* rp = &res.x;
    #pragma unroll
    for (int j = 0; j < 4; j++) {
        float val = (o[j] - m[j]) * rsqrtf(vr[j] + BN_EPS) * g[j] + bb[j];
        val = val > 0.f ? val : (__expf(val) - 1.f);
        val += sk[j];
        rp[j] = f2bf(val);
    }
    *reinterpret_cast<ushort4*>(&out[(size_t)n * 256 + lane4]) = res;
}

// ---------------------------------------------------------------- aggregation H=1,C=32
__global__ __launch_bounds__(256) void agg32(const unsigned short* __restrict__ h3,
                                             const float* __restrict__ as,
                                             const float* __restrict__ ad,
                                             const int* __restrict__ indptr,
                                             const int* __restrict__ esrc,
                                             const float* __restrict__ b3,
                                             const unsigned short* __restrict__ xs,
                                             float* __restrict__ out, int N) {
    int t = threadIdx.x;
    int n = blockIdx.x * 4 + (t >> 6);
    if (n >= N) return;
    int lane = t & 63;
    int e_sub = lane >> 3, c4 = (lane & 7) * 4;
    int start = indptr[n], end = indptr[n + 1];
    float adn = ad[n];

    float4 acc = make_float4(0.f, 0.f, 0.f, 0.f);
    float sm = 0.f;
    int i0 = start;
    for (; i0 + 16 <= end; i0 += 16) {
        int sA = esrc[i0 + e_sub];
        int sB = esrc[i0 + 8 + e_sub];
        float wA = __expf(lrelu(as[sA] + adn));
        float wB = __expf(lrelu(as[sB] + adn));
        sm += wA + wB;
        ushort4 hA = *reinterpret_cast<const ushort4*>(&h3[(size_t)sA * 32 + c4]);
        ushort4 hB = *reinterpret_cast<const ushort4*>(&h3[(size_t)sB * 32 + c4]);
        acc.x = fmaf(wA, bf2f(hA.x), acc.x); acc.y = fmaf(wA, bf2f(hA.y), acc.y);
        acc.z = fmaf(wA, bf2f(hA.z), acc.z); acc.w = fmaf(wA, bf2f(hA.w), acc.w);
        acc.x = fmaf(wB, bf2f(hB.x), acc.x); acc.y = fmaf(wB, bf2f(hB.y), acc.y);
        acc.z = fmaf(wB, bf2f(hB.z), acc.z); acc.w = fmaf(wB, bf2f(hB.w), acc.w);
    }
    for (; i0 < end; i0 += 8) {
        int idx = i0 + e_sub;
        bool valid = idx < end;
        if (valid) {
            int s = esrc[idx];
            float w = __expf(lrelu(as[s] + adn));
            sm += w;
            ushort4 hv = *reinterpret_cast<const ushort4*>(&h3[(size_t)s * 32 + c4]);
            acc.x = fmaf(w, bf2f(hv.x), acc.x);
            acc.y = fmaf(w, bf2f(hv.y), acc.y);
            acc.z = fmaf(w, bf2f(hv.z), acc.z);
            acc.w = fmaf(w, bf2f(hv.w), acc.w);
        }
    }
    #pragma unroll
    for (int off = 8; off < 64; off <<= 1) {
        sm    += __shfl_xor(sm, off);
        acc.x += __shfl_xor(acc.x, off);
        acc.y += __shfl_xor(acc.y, off);
        acc.z += __shfl_xor(acc.z, off);
        acc.w += __shfl_xor(acc.w, off);
    }
    if (e_sub == 0) {
        float il = 1.f / (sm + 1e-16f);
        float4 bv = *reinterpret_cast<const float4*>(&b3[c4]);
        ushort4 xv = *reinterpret_cast<const ushort4*>(&xs[(size_t)n * 32 + c4]);
        float4 o;
        o.x = acc.x * il + bv.x + bf2f(xv.x);
        o.y = acc.y * il + bv.y + bf2f(xv.y);
        o.z = acc.z * il + bv.z + bf2f(xv.z);
        o.w = acc.w * il + bv.w + bf2f(xv.w);
        *reinterpret_cast<float4*>(&out[(size_t)n * 32 + c4]) = o;
    }
}

// ---------------------------------------------------------------- launch
extern "C" void kernel_launch(void* const* d_in, const int* in_sizes, int n_in,
                              void* d_out, int out_size, void* d_ws, size_t ws_size,
                              hipStream_t stream) {
    const float* x      = (const float*)d_in[0];
    const int*   eidx   = (const int*)  d_in[1];
    const float* W1     = (const float*)d_in[2];
    const float* a_src1 = (const float*)d_in[3];
    const float* a_dst1 = (const float*)d_in[4];
    const float* b1     = (const float*)d_in[5];
    const float* bn1_g  = (const float*)d_in[6];
    const float* bn1_b  = (const float*)d_in[7];
    const float* bn1_m  = (const float*)d_in[8];
    const float* bn1_v  = (const float*)d_in[9];
    const float* W2     = (const float*)d_in[10];
    const float* a_src2 = (const float*)d_in[11];
    const float* a_dst2 = (const float*)d_in[12];
    const float* b2     = (const float*)d_in[13];
    const float* bn2_g  = (const float*)d_in[14];
    const float* bn2_b  = (const float*)d_in[15];
    const float* bn2_m  = (const float*)d_in[16];
    const float* bn2_v  = (const float*)d_in[17];
    const float* W3     = (const float*)d_in[18];
    const float* a_src3 = (const float*)d_in[19];
    const float* a_dst3 = (const float*)d_in[20];
    const float* b3     = (const float*)d_in[21];
    const float* Ws1    = (const float*)d_in[22];
    const float* bs1    = (const float*)d_in[23];
    const float* Ws2    = (const float*)d_in[24];
    const float* bs2    = (const float*)d_in[25];

    const int N = in_sizes[0] / 128;   // 50000
    const int E = in_sizes[1] / 2;     // 800000
    const int Etot = E + N;
    const int NB = (N + 255) >> 8;     // 196 buckets
    const int* srcl = eidx;
    const int* dstl = eidx + E;

    char* ws = (char*)d_ws;
    size_t off = 0;
    auto alloc = [&](size_t bytes) -> void* {
        void* p = ws + off;
        off += (bytes + 255) & ~(size_t)255;
        return p;
    };
    unsigned short* xb    = (unsigned short*)alloc((size_t)N * 128 * 2);
    unsigned short* feat  = (unsigned short*)alloc((size_t)N * 256 * 2); // x0 skip (bf16)
    unsigned short* hbuf  = (unsigned short*)alloc((size_t)N * 256 * 2); // gemm h output (bf16)
    unsigned char*  hq    = (unsigned char*)alloc((size_t)N * 256);     // fp8 copy for gathers
    unsigned short* h2b   = (unsigned short*)alloc((size_t)N * 256 * 2); // layer-1 agg out
    unsigned short* featb = (unsigned short*)alloc((size_t)N * 256 * 2); // layer-2 agg out
    unsigned short* xsbuf = (unsigned short*)alloc((size_t)N * 32 * 2);  // xs skip (bf16)
    unsigned short* h3b   = (unsigned short*)alloc((size_t)N * 32 * 2);
    float*          asb   = (float*)alloc((size_t)N * 8 * 4);
    float*          adb   = (float*)alloc((size_t)N * 8 * 4);
    unsigned short* Wcat1 = (unsigned short*)alloc((size_t)512 * 128 * 2); // [W1t; Ws1t]
    unsigned short* Wcat2 = (unsigned short*)alloc((size_t)288 * 256 * 2); // [W2t; Ws2t]
    unsigned short* W3t   = (unsigned short*)alloc((size_t)32 * 256 * 2);
    int* gHist   = (int*)alloc((size_t)NB * 4);
    int* bases   = (int*)alloc((size_t)NB * 4);
    int* gCursor = (int*)alloc((size_t)NB * 4);
    unsigned int* bktEdges = (unsigned int*)alloc((size_t)Etot * 4);
    int* indptr  = (int*)alloc((size_t)(N + 1) * 4);
    int* esrc    = (int*)alloc((size_t)Etot * 4);
    (void)ws_size; (void)n_in; (void)out_size;

    // ---- CSR build (bucketed multi-split)
    hipMemsetAsync(gHist, 0, (size_t)NB * 4, stream);
    bucket_count<<<256, 256, 0, stream>>>(dstl, E, N, NB, gHist);
    bucket_scan<<<1, 256, 0, stream>>>(gHist, bases, gCursor, NB);
    bucket_scatter<<<(Etot + 4095) / 4096, 256, 0, stream>>>(srcl, dstl, E, N, NB,
                                                             gCursor, bktEdges);
    bucket_to_csr<<<NB, 256, 0, stream>>>(bktEdges, bases, gCursor, indptr, esrc,
                                          N, NB, Etot);

    // ---- convert inputs (x -> bf16, weights -> transposed bf16) in one dispatch
    int n4x = N * 128 / 4;
    prep_all<<<(n4x + 147456 + 255) / 256, 256, 0, stream>>>(x, xb, n4x,
                                                             W1, Ws1, W2, Ws2, W3,
                                                             Wcat1, Wcat2, W3t);

    int gy128 = (N + 127) / 128;
    int gn4 = (N + 3) / 4;

    // ---- layer 1: fused [h1 | x0] = x @ [W1 | Ws1]  (+ fp8 copy of h1)
    gemm_tile<<<dim3(4, gy128), 256, 0, stream>>>(xb, Wcat1, hbuf, hq, feat, bs1,
                                                  N, 128, 512, 256, 256, 256);
    alpha256<<<gn4, 256, 0, stream>>>(hbuf, a_src1, a_dst1, asb, adb, N);
    agg256<1><<<gn4, 256, 0, stream>>>(hq, asb, adb, indptr, esrc, b1,
                                       bn1_g, bn1_b, bn1_m, bn1_v, feat, h2b, N);

    // ---- layer 2: fused [h2 | xs] = h @ [W2 | Ws2]  (+ fp8 copy of h2)
    gemm_tile<<<dim3(3, gy128), 256, 0, stream>>>(h2b, Wcat2, hbuf, hq, xsbuf, bs2,
                                                  N, 256, 288, 256, 256, 32);
    alpha256<<<gn4, 256, 0, stream>>>(hbuf, a_src2, a_dst2, asb, adb, N);
    agg256<0><<<gn4, 256, 0, stream>>>(hq, asb, adb, indptr, esrc, b2,
                                       bn2_g, bn2_b, bn2_m, bn2_v, nullptr, featb, N);

    // ---- layer 3: tiled GEMM (NCtot=32)
    gemm_tile<<<dim3(1, gy128), 256, 0, stream>>>(featb, W3t, h3b, nullptr, h3b, nullptr,
                                                  N, 256, 32, 32, 32, 32);
    alpha32<<<(N + 31) / 32, 256, 0, stream>>>(h3b, a_src3, a_dst3, asb, adb, N);
    agg32<<<gn4, 256, 0, stream>>>(h3b, asb, adb, indptr, esrc, b3, xsbuf,
                                   (float*)d_out, N);
}

// Round 12
// 404.460 us; speedup vs baseline: 1.2838x; 1.0165x over previous
//
#include <hip/hip_runtime.h>
#include <hip/hip_bf16.h>

#define NEG_SLOPE 0.2f
#define BN_EPS 1e-5f
#define BSH 8              // bucket shift: 256 nodes per bucket
#define STASH_CAP 6400     // K4 LDS stash entries (mean ~4600, +27 sigma)

typedef __attribute__((ext_vector_type(8))) short bf16x8;
typedef __attribute__((ext_vector_type(4))) float f32x4;
typedef __attribute__((ext_vector_type(2))) float f32x2;

#if defined(__has_builtin)
#if __has_builtin(__builtin_amdgcn_cvt_f32_fp8) && __has_builtin(__builtin_amdgcn_cvt_pk_fp8_f32)
#define HW_FP8 1
#endif
#if __has_builtin(__builtin_amdgcn_cvt_pk_f32_fp8)
#define HW_FP8_PK 1
#endif
#endif

__device__ __forceinline__ float bf2f(unsigned short u) {
    union { unsigned int i; float f; } x;
    x.i = ((unsigned int)u) << 16;
    return x.f;
}
__device__ __forceinline__ unsigned short f2bf(float f) {
    __hip_bfloat16 b = __float2bfloat16(f);
    return *reinterpret_cast<unsigned short*>(&b);
}
__device__ __forceinline__ float lrelu(float v) {
    return v > 0.f ? v : NEG_SLOPE * v;
}
__device__ __forceinline__ void gload_lds16(const void* g, void* l) {
    __builtin_amdgcn_global_load_lds(
        (const __attribute__((address_space(1))) unsigned int*)(g),
        (__attribute__((address_space(3))) unsigned int*)(l),
        16, 0, 0);
}

// ---- fp8 e4m3 (OCP) encode/decode: HW path + software fallback
__device__ __forceinline__ unsigned char f8enc(float f) {
#ifdef HW_FP8
    int p = __builtin_amdgcn_cvt_pk_fp8_f32(f, 0.f, 0, false);
    return (unsigned char)(p & 0xff);
#else
    float a = fabsf(f);
    unsigned int sign = (__float_as_uint(f) >> 31) << 7;
    if (a < 0.0009765625f) return (unsigned char)sign;
    a = fminf(a, 448.f);
    unsigned int bits = __float_as_uint(a);
    int e = (int)((bits >> 23) & 0xff) - 127;
    unsigned int mant = bits & 0x7fffff;
    if (e < -6) {
        int q = (int)(a * 512.f + 0.5f);
        if (q >= 8) return (unsigned char)(sign | 0x08);
        return (unsigned char)(sign | q);
    }
    unsigned int m = mant >> 20;
    unsigned int rem = mant & 0xfffff;
    if (rem > 0x80000 || (rem == 0x80000 && (m & 1))) m++;
    if (m == 8) { m = 0; e++; }
    if (e > 8) { e = 8; m = 6; }
    return (unsigned char)(sign | ((unsigned int)(e + 7) << 3) | m);
#endif
}
template <int SEL>
__device__ __forceinline__ float f8dec(unsigned int w) {
#ifdef HW_FP8
    return __builtin_amdgcn_cvt_f32_fp8(w, SEL);
#else
    unsigned int b = (w >> (SEL * 8)) & 0xff;
    unsigned int s = b >> 7, em = b & 0x7f;
    float mag;
    if (em >= 8) {
        unsigned int bits = (((em >> 3) + 120) << 23) | ((em & 7) << 20);
        mag = __uint_as_float(bits);
    } else {
        mag = (float)em * 0.001953125f;
    }
    return s ? -mag : mag;
#endif
}
// 4x fp8 -> fma into float4 (packed HW decode when available)
__device__ __forceinline__ void fma_f8x4(float we, unsigned int wv, float4& acc) {
#ifdef HW_FP8_PK
    f32x2 lo = __builtin_amdgcn_cvt_pk_f32_fp8((int)wv, false);
    f32x2 hi = __builtin_amdgcn_cvt_pk_f32_fp8((int)wv, true);
    acc.x = fmaf(we, lo[0], acc.x);
    acc.y = fmaf(we, lo[1], acc.y);
    acc.z = fmaf(we, hi[0], acc.z);
    acc.w = fmaf(we, hi[1], acc.w);
#else
    acc.x = fmaf(we, f8dec<0>(wv), acc.x);
    acc.y = fmaf(we, f8dec<1>(wv), acc.y);
    acc.z = fmaf(we, f8dec<2>(wv), acc.z);
    acc.w = fmaf(we, f8dec<3>(wv), acc.w);
#endif
}

__device__ __forceinline__ int block_scan_incl(int v, int t) {
    int lane = t & 63, w = t >> 6;
    int sv = v;
    #pragma unroll
    for (int off = 1; off < 64; off <<= 1) {
        int u = __shfl_up(sv, off);
        if (lane >= off) sv += u;
    }
    __shared__ int ws_[4];
    if (lane == 63) ws_[w] = sv;
    __syncthreads();
    if (t == 0) {
        int a = 0;
        #pragma unroll
        for (int k = 0; k < 4; k++) { int x = ws_[k]; ws_[k] = a; a += x; }
    }
    __syncthreads();
    return sv + ws_[w];
}

// ================================================================ CSR build (bucketed multi-split)
__global__ __launch_bounds__(256) void bucket_count(const int* __restrict__ dstl,
                                                    int E, int N, int NB,
                                                    int* __restrict__ gHist) {
    __shared__ int h[256];
    int t = threadIdx.x;
    h[t] = 0;
    __syncthreads();
    int Etot = E + N;
    for (int i = blockIdx.x * 256 + t; i < Etot; i += gridDim.x * 256) {
        int d = (i < E) ? dstl[i] : (i - E);
        atomicAdd(&h[d >> BSH], 1);
    }
    __syncthreads();
    if (t < NB && h[t]) atomicAdd(&gHist[t], h[t]);
}

__global__ __launch_bounds__(256) void bucket_scan(const int* __restrict__ gHist,
                                                   int* __restrict__ bases,
                                                   int* __restrict__ gCursor, int NB) {
    int t = threadIdx.x;
    int v = (t < NB) ? gHist[t] : 0;
    int incl = block_scan_incl(v, t);
    if (t < NB) { bases[t] = incl - v; gCursor[t] = incl - v; }
}

__global__ __launch_bounds__(256) void bucket_scatter(const int* __restrict__ srcl,
                                                      const int* __restrict__ dstl,
                                                      int E, int N, int NB,
                                                      int* __restrict__ gCursor,
                                                      unsigned int* __restrict__ bktEdges) {
    __shared__ unsigned int stage[4096];
    __shared__ int hist[256];
    __shared__ int bexcl[257];
    __shared__ int curk[256];
    __shared__ int gbase[256];
    int t = threadIdx.x;
    int Etot = E + N;
    int begin = blockIdx.x * 4096;

    hist[t] = 0;
    __syncthreads();

    unsigned int ent[16];
    int eb[16];
    #pragma unroll
    for (int k = 0; k < 16; k++) {
        int i = begin + k * 256 + t;
        if (i < Etot) {
            int s, d;
            if (i < E) { s = srcl[i]; d = dstl[i]; }
            else       { s = d = i - E; }
            eb[k] = d >> BSH;
            ent[k] = ((unsigned int)s << BSH) | (unsigned int)(d & 255);
            atomicAdd(&hist[eb[k]], 1);
        } else eb[k] = -1;
    }
    __syncthreads();

    int v = hist[t];
    int incl = block_scan_incl(v, t);
    bexcl[t] = incl - v;
    curk[t] = incl - v;
    if (t == 255) bexcl[256] = incl;
    __syncthreads();

    #pragma unroll
    for (int k = 0; k < 16; k++) {
        if (eb[k] >= 0) {
            int slot = atomicAdd(&curk[eb[k]], 1);
            stage[slot] = ent[k];
        }
    }
    if (t < NB) {
        int cnt = hist[t];
        gbase[t] = cnt ? atomicAdd(&gCursor[t], cnt) : 0;
    }
    __syncthreads();

    int total = bexcl[256];
    for (int p = t; p < total; p += 256) {
        int lo = 0, hi = NB - 1;
        while (lo < hi) {
            int mid = (lo + hi + 1) >> 1;
            if (bexcl[mid] <= p) lo = mid; else hi = mid - 1;
        }
        bktEdges[gbase[lo] + (p - bexcl[lo])] = stage[p];
    }
}

__global__ __launch_bounds__(256) void bucket_to_csr(const unsigned int* __restrict__ bktEdges,
                                                     const int* __restrict__ bases,
                                                     const int* __restrict__ gCursor,
                                                     int* __restrict__ indptr,
                                                     int* __restrict__ esrc,
                                                     int N, int NB, int Etot) {
    __shared__ int nh[256];
    __shared__ int ncur[256];
    __shared__ unsigned int stash[STASH_CAP];
    int b = blockIdx.x, t = threadIdx.x;
    int base = bases[b];
    int cnt = gCursor[b] - base;
    int nodeBase = b << BSH;

    nh[t] = 0;
    __syncthreads();
    for (int p = t; p < cnt; p += 256) {
        unsigned int e = bktEdges[base + p];
        if (p < STASH_CAP) stash[p] = e;
        atomicAdd(&nh[e & 255], 1);
    }
    __syncthreads();
    int v = nh[t];
    int incl = block_scan_incl(v, t);
    int excl = incl - v;
    ncur[t] = excl;
    if (nodeBase + t < N) indptr[nodeBase + t] = base + excl;
    __syncthreads();
    for (int p = t; p < cnt; p += 256) {
        unsigned int e = (p < STASH_CAP) ? stash[p] : bktEdges[base + p];
        int slot = atomicAdd(&ncur[e & 255], 1);
        esrc[base + slot] = (int)(e >> BSH);
    }
    if (b == 0 && t == 0) indptr[N] = Etot;
}

// ---------------------------------------------------------------- prep: x->bf16 + all weight transposes
__global__ __launch_bounds__(256) void prep_all(const float* __restrict__ x,
                                                unsigned short* __restrict__ xb, int n4x,
                                                const float* __restrict__ W1,
                                                const float* __restrict__ Ws1,
                                                const float* __restrict__ W2,
                                                const float* __restrict__ Ws2,
                                                const float* __restrict__ W3,
                                                unsigned short* __restrict__ Wcat1,
                                                unsigned short* __restrict__ Wcat2,
                                                unsigned short* __restrict__ W3t) {
    int i = blockIdx.x * 256 + threadIdx.x;
    if (i < n4x) {
        float4 v = reinterpret_cast<const float4*>(x)[i];
        ushort4 o;
        o.x = f2bf(v.x); o.y = f2bf(v.y); o.z = f2bf(v.z); o.w = f2bf(v.w);
        reinterpret_cast<ushort4*>(xb)[i] = o;
        return;
    }
    int j = i - n4x;
    if (j < 32768) {
        int m = j >> 7, k = j & 127;
        Wcat1[j] = f2bf(W1[k * 256 + m]);
    } else if (j < 65536) {
        int q = j - 32768; int m = q >> 7, k = q & 127;
        Wcat1[32768 + q] = f2bf(Ws1[k * 256 + m]);
    } else if (j < 131072) {
        int q = j - 65536; int m = q >> 8, k = q & 255;
        Wcat2[q] = f2bf(W2[k * 256 + m]);
    } else if (j < 139264) {
        int q = j - 131072; int m = q >> 8, k = q & 255;
        Wcat2[65536 + q] = f2bf(Ws2[k * 32 + m]);
    } else if (j < 147456) {
        int q = j - 139264; int m = q >> 8, k = q & 255;
        W3t[q] = f2bf(W3[k * 32 + m]);
    }
}

// ---------------------------------------------------------------- tiled MFMA GEMM (+fused alpha)
// 128x128 tile, BK=32, double-buffered LDS via global_load_lds(16B).
// Epilogue: col < split -> optional bf16 outBf, optional fp8 outQ;
//           col >= split -> bf16 outSk + biasSk.
// Fused alpha (aS != nullptr, blocks fully inside h region): each head's 32
// cols live inside one 128-col tile and each (row, head) is owned by exactly
// one wave -> per-head sums reduce with shfl_xor(1,2,4,8) within 16-lane
// groups and plain stores (no atomics, no init).
__global__ __launch_bounds__(256) void gemm_tile(const unsigned short* __restrict__ A,
                                                 const unsigned short* __restrict__ Bt,
                                                 unsigned short* __restrict__ outBf,
                                                 unsigned char* __restrict__ outQ,
                                                 unsigned short* __restrict__ outSk,
                                                 const float* __restrict__ biasSk,
                                                 const float* __restrict__ aS,
                                                 const float* __restrict__ aD,
                                                 float* __restrict__ asOut,
                                                 float* __restrict__ adOut,
                                                 int M, int K, int NCtot, int split,
                                                 int ldBf, int ldSk) {
    __shared__ __align__(16) char smem[2][2][8192];
    int t = threadIdx.x;
    int w = t >> 6, lane = t & 63;
    int l16 = lane & 15, quad = lane >> 4;
    int warp_r = w >> 1, warp_c = w & 1;
    int rowBase = blockIdx.y * 128;
    int colBase = blockIdx.x * 128;

    int row_l = t & 127;
    int jchunk = t >> 7;
    int arow_st = rowBase + row_l; if (arow_st >= M) arow_st = M - 1;
    int bcol_st = colBase + row_l; if (bcol_st >= NCtot) bcol_st = NCtot - 1;
    const unsigned short* aRow = A + (size_t)arow_st * K;
    const unsigned short* bRow = Bt + (size_t)bcol_st * K;

    f32x4 acc[4][4];
    #pragma unroll
    for (int i = 0; i < 4; i++)
        #pragma unroll
        for (int j = 0; j < 4; j++) acc[i][j] = (f32x4){0.f, 0.f, 0.f, 0.f};

    auto stage = [&](int buf, int k0) {
        #pragma unroll
        for (int j = 0; j < 2; j++) {
            int chunk = j * 2 + jchunk;
            gload_lds16(aRow + k0 + chunk * 8, &smem[buf][0][(size_t)j * 4096 + (size_t)t * 16]);
            gload_lds16(bRow + k0 + chunk * 8, &smem[buf][1][(size_t)j * 4096 + (size_t)t * 16]);
        }
    };

    stage(0, 0);
    __syncthreads();
    int niter = K >> 5;
    for (int it = 0; it < niter; ++it) {
        if (it + 1 < niter) stage((it + 1) & 1, (it + 1) << 5);
        const char* Ab = &smem[it & 1][0][0];
        const char* Bb = &smem[it & 1][1][0];
        bf16x8 a[4], b[4];
        #pragma unroll
        for (int i = 0; i < 4; i++)
            a[i] = *reinterpret_cast<const bf16x8*>(Ab + quad * 2048 + (warp_r * 64 + i * 16 + l16) * 16);
        #pragma unroll
        for (int j = 0; j < 4; j++)
            b[j] = *reinterpret_cast<const bf16x8*>(Bb + quad * 2048 + (warp_c * 64 + j * 16 + l16) * 16);
        #pragma unroll
        for (int i = 0; i < 4; i++)
            #pragma unroll
            for (int j = 0; j < 4; j++)
                acc[i][j] = __builtin_amdgcn_mfma_f32_16x16x32_bf16(a[i], b[j], acc[i][j], 0, 0, 0);
        __syncthreads();
    }

    // ---- fused alpha (h-region blocks only)
    if (aS && colBase < split) {
        int c0 = colBase + warp_c * 64 + l16;
        int hbase = (colBase + warp_c * 64) >> 5;
        float as0 = aS[c0],      ad0 = aD[c0];
        float as1 = aS[c0 + 16], ad1 = aD[c0 + 16];
        float as2 = aS[c0 + 32], ad2 = aD[c0 + 32];
        float as3 = aS[c0 + 48], ad3 = aD[c0 + 48];
        #pragma unroll
        for (int i = 0; i < 4; i++) {
            #pragma unroll
            for (int r = 0; r < 4; r++) {
                float va0 = acc[i][0][r] * as0 + acc[i][1][r] * as1;
                float vd0 = acc[i][0][r] * ad0 + acc[i][1][r] * ad1;
                float va1 = acc[i][2][r] * as2 + acc[i][3][r] * as3;
                float vd1 = acc[i][2][r] * ad2 + acc[i][3][r] * ad3;
                #pragma unroll
                for (int off = 1; off < 16; off <<= 1) {
                    va0 += __shfl_xor(va0, off);
                    vd0 += __shfl_xor(vd0, off);
                    va1 += __shfl_xor(va1, off);
                    vd1 += __shfl_xor(vd1, off);
                }
                int row = rowBase + warp_r * 64 + i * 16 + quad * 4 + r;
                if (l16 == 0 && row < M) {
                    asOut[row * 8 + hbase]     = va0;
                    adOut[row * 8 + hbase]     = vd0;
                    asOut[row * 8 + hbase + 1] = va1;
                    adOut[row * 8 + hbase + 1] = vd1;
                }
            }
        }
    }

    #pragma unroll
    for (int i = 0; i < 4; i++) {
        #pragma unroll
        for (int r = 0; r < 4; r++) {
            int row = rowBase + warp_r * 64 + i * 16 + quad * 4 + r;
            if (row >= M) continue;
            #pragma unroll
            for (int j = 0; j < 4; j++) {
                int c = colBase + warp_c * 64 + j * 16 + l16;
                if (c >= NCtot) continue;
                float v = acc[i][j][r];
                if (c < split) {
                    if (outBf) outBf[(size_t)row * ldBf + c] = f2bf(v);
                    if (outQ)  outQ[(size_t)row * ldBf + c] = f8enc(v);
                } else {
                    outSk[(size_t)row * ldSk + (c - split)] = f2bf(v + biasSk[c - split]);
                }
            }
        }
    }
}

// ---------------------------------------------------------------- alpha (H=1,C=32), 8 nodes/wave
__global__ __launch_bounds__(256) void alpha32(const unsigned short* __restrict__ h,
                                               const float* __restrict__ a_s,
                                               const float* __restrict__ a_d,
                                               float* __restrict__ as_out,
                                               float* __restrict__ ad_out, int N) {
    int t = threadIdx.x;
    int lane = t & 63;
    int n = blockIdx.x * 32 + (t >> 6) * 8 + (lane >> 3);
    int c4 = (lane & 7) * 4;
    if (n >= N) return;
    ushort4 hv = *reinterpret_cast<const ushort4*>(&h[(size_t)n * 32 + c4]);
    float4 sv = *reinterpret_cast<const float4*>(&a_s[c4]);
    float4 dv = *reinterpret_cast<const float4*>(&a_d[c4]);
    float h0 = bf2f(hv.x), h1 = bf2f(hv.y), h2 = bf2f(hv.z), h3 = bf2f(hv.w);
    float va = h0 * sv.x + h1 * sv.y + h2 * sv.z + h3 * sv.w;
    float vd = h0 * dv.x + h1 * dv.y + h2 * dv.z + h3 * dv.w;
    #pragma unroll
    for (int off = 1; off < 8; off <<= 1) {
        va += __shfl_xor(va, off);
        vd += __shfl_xor(vd, off);
    }
    if ((lane & 7) == 0) {
        as_out[n] = va;
        ad_out[n] = vd;
    }
}

// ---------------------------------------------------------------- aggregation H=8,C=32 (fp8 gather)
template <int MODE>
__global__ __launch_bounds__(256) void agg256(const unsigned char* __restrict__ hq,
                                              const float* __restrict__ as,
                                              const float* __restrict__ ad,
                                              const int* __restrict__ indptr,
                                              const int* __restrict__ esrc,
                                              const float* __restrict__ bias,
                                              const float* __restrict__ bn_g,
                                              const float* __restrict__ bn_b,
                                              const float* __restrict__ bn_m,
                                              const float* __restrict__ bn_v,
                                              const unsigned short* __restrict__ skip,
                                              unsigned short* __restrict__ out, int N) {
    int t = threadIdx.x;
    int n = blockIdx.x * 4 + (t >> 6);
    if (n >= N) return;
    int lane = t & 63;
    int e_sub = lane >> 3, h_sub = lane & 7;
    int ch_head = lane >> 3;
    int lane4 = lane * 4;
    int start = indptr[n], end = indptr[n + 1];
    int cnt = end - start;

    float adh = ad[n * 8 + h_sub];

    float4 acc = make_float4(0.f, 0.f, 0.f, 0.f);
    float sm = 0.f;
    int nfull = cnt & ~7;
    int i0 = start;
    int s_l = 0; float w8 = 0.f;
    if (nfull) {
        s_l = esrc[i0 + e_sub];
        w8 = __expf(lrelu(as[s_l * 8 + h_sub] + adh));
    }
    while (i0 < start + nfull) {
        int s_cur = s_l;
        float w_cur = w8;
        i0 += 8;
        if (i0 < start + nfull) {
            s_l = esrc[i0 + e_sub];
            w8 = __expf(lrelu(as[s_l * 8 + h_sub] + adh));
        }
        sm += w_cur;
        unsigned int hv[8];
        #pragma unroll
        for (int e = 0; e < 8; e++) {
            int se = __shfl(s_cur, e * 8);
            hv[e] = *reinterpret_cast<const unsigned int*>(&hq[(size_t)se * 256 + lane4]);
        }
        #pragma unroll
        for (int e = 0; e < 8; e++) {
            float we = __shfl(w_cur, e * 8 + ch_head);
            fma_f8x4(we, hv[e], acc);
        }
    }
    int rem = cnt - nfull;
    if (rem) {
        int idx = i0 + e_sub;
        int s_r = esrc[idx < end ? idx : end - 1];
        float w_r = (idx < end) ? __expf(lrelu(as[s_r * 8 + h_sub] + adh)) : 0.f;
        sm += w_r;
        #pragma unroll
        for (int e = 0; e < 8; e++) {
            if (e < rem) {
                int se = __shfl(s_r, e * 8);
                float we = __shfl(w_r, e * 8 + ch_head);
                unsigned int hv = *reinterpret_cast<const unsigned int*>(&hq[(size_t)se * 256 + lane4]);
                fma_f8x4(we, hv, acc);
            }
        }
    }
    #pragma unroll
    for (int off = 8; off < 64; off <<= 1) sm += __shfl_xor(sm, off);
    float il = 1.f / (sm + 1e-16f);
    float il_c = __shfl(il, ch_head);

    float4 bv  = *reinterpret_cast<const float4*>(&bias[lane4]);
    float4 gv  = *reinterpret_cast<const float4*>(&bn_g[lane4]);
    float4 bbv = *reinterpret_cast<const float4*>(&bn_b[lane4]);
    float4 mv  = *reinterpret_cast<const float4*>(&bn_m[lane4]);
    float4 vv  = *reinterpret_cast<const float4*>(&bn_v[lane4]);
    float o[4] = {acc.x * il_c + bv.x, acc.y * il_c + bv.y,
                  acc.z * il_c + bv.z, acc.w * il_c + bv.w};
    float g[4] = {gv.x, gv.y, gv.z, gv.w}, bb[4] = {bbv.x, bbv.y, bbv.z, bbv.w};
    float m[4] = {mv.x, mv.y, mv.z, mv.w}, vr[4] = {vv.x, vv.y, vv.z, vv.w};
    float sk[4] = {0.f, 0.f, 0.f, 0.f};
    if (MODE == 1) {
        ushort4 s4 = *reinterpret_cast<const ushort4*>(&skip[(size_t)n * 256 + lane4]);
        sk[0] = bf2f(s4.x); sk[1] = bf2f(s4.y); sk[2] = bf2f(s4.z); sk[3] = bf2f(s4.w);
    }
    ushort4 res;
    unsigned short* rp = &res.x;
    #pragma unroll
    for (int j = 0; j < 4; j++) {
        float val = (o[j] - m[j]) * rsqrtf(vr[j] + BN_EPS) * g[j] + bb[j];
        val = val > 0.f ? val : (__expf(val) - 1.f);
        val += sk[j];
        rp[j] = f2bf(val);
    }
    *reinterpret_cast<ushort4*>(&out[(size_t)n * 256 + lane4]) = res;
}

// ---------------------------------------------------------------- aggregation H=1,C=32
__global__ __launch_bounds__(256) void agg32(const unsigned short* __restrict__ h3,
                                             const float* __restrict__ as,
                                             const float* __restrict__ ad,
                                             const int* __restrict__ indptr,
                                             const int* __restrict__ esrc,
                                             const float* __restrict__ b3,
                                             const unsigned short* __restrict__ xs,
                                             float* __restrict__ out, int N) {
    int t = threadIdx.x;
    int n = blockIdx.x * 4 + (t >> 6);
    if (n >= N) return;
    int lane = t & 63;
    int e_sub = lane >> 3, c4 = (lane & 7) * 4;
    int start = indptr[n], end = indptr[n + 1];
    float adn = ad[n];

    float4 acc = make_float4(0.f, 0.f, 0.f, 0.f);
    float sm = 0.f;
    int i0 = start;
    for (; i0 + 16 <= end; i0 += 16) {
        int sA = esrc[i0 + e_sub];
        int sB = esrc[i0 + 8 + e_sub];
        float wA = __expf(lrelu(as[sA] + adn));
        float wB = __expf(lrelu(as[sB] + adn));
        sm += wA + wB;
        ushort4 hA = *reinterpret_cast<const ushort4*>(&h3[(size_t)sA * 32 + c4]);
        ushort4 hB = *reinterpret_cast<const ushort4*>(&h3[(size_t)sB * 32 + c4]);
        acc.x = fmaf(wA, bf2f(hA.x), acc.x); acc.y = fmaf(wA, bf2f(hA.y), acc.y);
        acc.z = fmaf(wA, bf2f(hA.z), acc.z); acc.w = fmaf(wA, bf2f(hA.w), acc.w);
        acc.x = fmaf(wB, bf2f(hB.x), acc.x); acc.y = fmaf(wB, bf2f(hB.y), acc.y);
        acc.z = fmaf(wB, bf2f(hB.z), acc.z); acc.w = fmaf(wB, bf2f(hB.w), acc.w);
    }
    for (; i0 < end; i0 += 8) {
        int idx = i0 + e_sub;
        bool valid = idx < end;
        if (valid) {
            int s = esrc[idx];
            float w = __expf(lrelu(as[s] + adn));
            sm += w;
            ushort4 hv = *reinterpret_cast<const ushort4*>(&h3[(size_t)s * 32 + c4]);
            acc.x = fmaf(w, bf2f(hv.x), acc.x);
            acc.y = fmaf(w, bf2f(hv.y), acc.y);
            acc.z = fmaf(w, bf2f(hv.z), acc.z);
            acc.w = fmaf(w, bf2f(hv.w), acc.w);
        }
    }
    #pragma unroll
    for (int off = 8; off < 64; off <<= 1) {
        sm    += __shfl_xor(sm, off);
        acc.x += __shfl_xor(acc.x, off);
        acc.y += __shfl_xor(acc.y, off);
        acc.z += __shfl_xor(acc.z, off);
        acc.w += __shfl_xor(acc.w, off);
    }
    if (e_sub == 0) {
        float il = 1.f / (sm + 1e-16f);
        float4 bv = *reinterpret_cast<const float4*>(&b3[c4]);
        ushort4 xv = *reinterpret_cast<const ushort4*>(&xs[(size_t)n * 32 + c4]);
        float4 o;
        o.x = acc.x * il + bv.x + bf2f(xv.x);
        o.y = acc.y * il + bv.y + bf2f(xv.y);
        o.z = acc.z * il + bv.z + bf2f(xv.z);
        o.w = acc.w * il + bv.w + bf2f(xv.w);
        *reinterpret_cast<float4*>(&out[(size_t)n * 32 + c4]) = o;
    }
}

// ---------------------------------------------------------------- launch
extern "C" void kernel_launch(void* const* d_in, const int* in_sizes, int n_in,
                              void* d_out, int out_size, void* d_ws, size_t ws_size,
                              hipStream_t stream) {
    const float* x      = (const float*)d_in[0];
    const int*   eidx   = (const int*)  d_in[1];
    const float* W1     = (const float*)d_in[2];
    const float* a_src1 = (const float*)d_in[3];
    const float* a_dst1 = (const float*)d_in[4];
    const float* b1     = (const float*)d_in[5];
    const float* bn1_g  = (const float*)d_in[6];
    const float* bn1_b  = (const float*)d_in[7];
    const float* bn1_m  = (const float*)d_in[8];
    const float* bn1_v  = (const float*)d_in[9];
    const float* W2     = (const float*)d_in[10];
    const float* a_src2 = (const float*)d_in[11];
    const float* a_dst2 = (const float*)d_in[12];
    const float* b2     = (const float*)d_in[13];
    const float* bn2_g  = (const float*)d_in[14];
    const float* bn2_b  = (const float*)d_in[15];
    const float* bn2_m  = (const float*)d_in[16];
    const float* bn2_v  = (const float*)d_in[17];
    const float* W3     = (const float*)d_in[18];
    const float* a_src3 = (const float*)d_in[19];
    const float* a_dst3 = (const float*)d_in[20];
    const float* b3     = (const float*)d_in[21];
    const float* Ws1    = (const float*)d_in[22];
    const float* bs1    = (const float*)d_in[23];
    const float* Ws2    = (const float*)d_in[24];
    const float* bs2    = (const float*)d_in[25];

    const int N = in_sizes[0] / 128;   // 50000
    const int E = in_sizes[1] / 2;     // 800000
    const int Etot = E + N;
    const int NB = (N + 255) >> 8;     // 196 buckets
    const int* srcl = eidx;
    const int* dstl = eidx + E;

    char* ws = (char*)d_ws;
    size_t off = 0;
    auto alloc = [&](size_t bytes) -> void* {
        void* p = ws + off;
        off += (bytes + 255) & ~(size_t)255;
        return p;
    };
    unsigned short* xb    = (unsigned short*)alloc((size_t)N * 128 * 2);
    unsigned short* feat  = (unsigned short*)alloc((size_t)N * 256 * 2); // x0 skip (bf16)
    unsigned char*  hq    = (unsigned char*)alloc((size_t)N * 256);     // fp8 h for gathers
    unsigned short* h2b   = (unsigned short*)alloc((size_t)N * 256 * 2); // layer-1 agg out
    unsigned short* featb = (unsigned short*)alloc((size_t)N * 256 * 2); // layer-2 agg out
    unsigned short* xsbuf = (unsigned short*)alloc((size_t)N * 32 * 2);  // xs skip (bf16)
    unsigned short* h3b   = (unsigned short*)alloc((size_t)N * 32 * 2);
    float*          asb   = (float*)alloc((size_t)N * 8 * 4);
    float*          adb   = (float*)alloc((size_t)N * 8 * 4);
    unsigned short* Wcat1 = (unsigned short*)alloc((size_t)512 * 128 * 2); // [W1t; Ws1t]
    unsigned short* Wcat2 = (unsigned short*)alloc((size_t)288 * 256 * 2); // [W2t; Ws2t]
    unsigned short* W3t   = (unsigned short*)alloc((size_t)32 * 256 * 2);
    int* gHist   = (int*)alloc((size_t)NB * 4);
    int* bases   = (int*)alloc((size_t)NB * 4);
    int* gCursor = (int*)alloc((size_t)NB * 4);
    unsigned int* bktEdges = (unsigned int*)alloc((size_t)Etot * 4);
    int* indptr  = (int*)alloc((size_t)(N + 1) * 4);
    int* esrc    = (int*)alloc((size_t)Etot * 4);
    (void)ws_size; (void)n_in; (void)out_size;

    // ---- CSR build (bucketed multi-split)
    hipMemsetAsync(gHist, 0, (size_t)NB * 4, stream);
    bucket_count<<<256, 256, 0, stream>>>(dstl, E, N, NB, gHist);
    bucket_scan<<<1, 256, 0, stream>>>(gHist, bases, gCursor, NB);
    bucket_scatter<<<(Etot + 4095) / 4096, 256, 0, stream>>>(srcl, dstl, E, N, NB,
                                                             gCursor, bktEdges);
    bucket_to_csr<<<NB, 256, 0, stream>>>(bktEdges, bases, gCursor, indptr, esrc,
                                          N, NB, Etot);

    // ---- convert inputs (x -> bf16, weights -> transposed bf16)
    int n4x = N * 128 / 4;
    prep_all<<<(n4x + 147456 + 255) / 256, 256, 0, stream>>>(x, xb, n4x,
                                                             W1, Ws1, W2, Ws2, W3,
                                                             Wcat1, Wcat2, W3t);

    int gy128 = (N + 127) / 128;
    int gn4 = (N + 3) / 4;

    // ---- layer 1: fused [h1 | x0] = x @ [W1 | Ws1], alpha fused in epilogue
    gemm_tile<<<dim3(4, gy128), 256, 0, stream>>>(xb, Wcat1, nullptr, hq, feat, bs1,
                                                  a_src1, a_dst1, asb, adb,
                                                  N, 128, 512, 256, 256, 256);
    agg256<1><<<gn4, 256, 0, stream>>>(hq, asb, adb, indptr, esrc, b1,
                                       bn1_g, bn1_b, bn1_m, bn1_v, feat, h2b, N);

    // ---- layer 2: fused [h2 | xs] = h @ [W2 | Ws2], alpha fused in epilogue
    gemm_tile<<<dim3(3, gy128), 256, 0, stream>>>(h2b, Wcat2, nullptr, hq, xsbuf, bs2,
                                                  a_src2, a_dst2, asb, adb,
                                                  N, 256, 288, 256, 256, 32);
    agg256<0><<<gn4, 256, 0, stream>>>(hq, asb, adb, indptr, esrc, b2,
                                       bn2_g, bn2_b, bn2_m, bn2_v, nullptr, featb, N);

    // ---- layer 3: tiled GEMM (NCtot=32, bf16 out)
    gemm_tile<<<dim3(1, gy128), 256, 0, stream>>>(featb, W3t, h3b, nullptr, h3b, nullptr,
                                                  nullptr, nullptr, nullptr, nullptr,
                                                  N, 256, 32, 32, 32, 32);
    alpha32<<<(N + 31) / 32, 256, 0, stream>>>(h3b, a_src3, a_dst3, asb, adb, N);
    agg32<<<gn4, 256, 0, stream>>>(h3b, asb, adb, indptr, esrc, b3, xsbuf,
                                   (float*)d_out, N);
}

// Round 13
// 398.551 us; speedup vs baseline: 1.3028x; 1.0148x over previous
//
#include <hip/hip_runtime.h>
#include <hip/hip_bf16.h>

#define NEG_SLOPE 0.2f
#define BN_EPS 1e-5f
#define BSH 8              // bucket shift: 256 nodes per bucket
#define STASH_CAP 6400     // K4 LDS stash entries (mean ~4600, +27 sigma)

typedef __attribute__((ext_vector_type(8))) short bf16x8;
typedef __attribute__((ext_vector_type(4))) float f32x4;
typedef __attribute__((ext_vector_type(2))) float f32x2;

#if defined(__has_builtin)
#if __has_builtin(__builtin_amdgcn_cvt_f32_fp8) && __has_builtin(__builtin_amdgcn_cvt_pk_fp8_f32)
#define HW_FP8 1
#endif
#if __has_builtin(__builtin_amdgcn_cvt_pk_f32_fp8)
#define HW_FP8_PK 1
#endif
#endif

__device__ __forceinline__ float bf2f(unsigned short u) {
    union { unsigned int i; float f; } x;
    x.i = ((unsigned int)u) << 16;
    return x.f;
}
__device__ __forceinline__ unsigned short f2bf(float f) {
    __hip_bfloat16 b = __float2bfloat16(f);
    return *reinterpret_cast<unsigned short*>(&b);
}
__device__ __forceinline__ float lrelu(float v) {
    return v > 0.f ? v : NEG_SLOPE * v;
}
__device__ __forceinline__ void gload_lds16(const void* g, void* l) {
    __builtin_amdgcn_global_load_lds(
        (const __attribute__((address_space(1))) unsigned int*)(g),
        (__attribute__((address_space(3))) unsigned int*)(l),
        16, 0, 0);
}

// ---- fp8 e4m3 (OCP) encode/decode: HW path + software fallback
__device__ __forceinline__ unsigned char f8enc(float f) {
#ifdef HW_FP8
    int p = __builtin_amdgcn_cvt_pk_fp8_f32(f, 0.f, 0, false);
    return (unsigned char)(p & 0xff);
#else
    float a = fabsf(f);
    unsigned int sign = (__float_as_uint(f) >> 31) << 7;
    if (a < 0.0009765625f) return (unsigned char)sign;
    a = fminf(a, 448.f);
    unsigned int bits = __float_as_uint(a);
    int e = (int)((bits >> 23) & 0xff) - 127;
    unsigned int mant = bits & 0x7fffff;
    if (e < -6) {
        int q = (int)(a * 512.f + 0.5f);
        if (q >= 8) return (unsigned char)(sign | 0x08);
        return (unsigned char)(sign | q);
    }
    unsigned int m = mant >> 20;
    unsigned int rem = mant & 0xfffff;
    if (rem > 0x80000 || (rem == 0x80000 && (m & 1))) m++;
    if (m == 8) { m = 0; e++; }
    if (e > 8) { e = 8; m = 6; }
    return (unsigned char)(sign | ((unsigned int)(e + 7) << 3) | m);
#endif
}
template <int SEL>
__device__ __forceinline__ float f8dec(unsigned int w) {
#ifdef HW_FP8
    return __builtin_amdgcn_cvt_f32_fp8(w, SEL);
#else
    unsigned int b = (w >> (SEL * 8)) & 0xff;
    unsigned int s = b >> 7, em = b & 0x7f;
    float mag;
    if (em >= 8) {
        unsigned int bits = (((em >> 3) + 120) << 23) | ((em & 7) << 20);
        mag = __uint_as_float(bits);
    } else {
        mag = (float)em * 0.001953125f;
    }
    return s ? -mag : mag;
#endif
}
__device__ __forceinline__ void fma_f8x4(float we, unsigned int wv, float4& acc) {
#ifdef HW_FP8_PK
    f32x2 lo = __builtin_amdgcn_cvt_pk_f32_fp8((int)wv, false);
    f32x2 hi = __builtin_amdgcn_cvt_pk_f32_fp8((int)wv, true);
    acc.x = fmaf(we, lo[0], acc.x);
    acc.y = fmaf(we, lo[1], acc.y);
    acc.z = fmaf(we, hi[0], acc.z);
    acc.w = fmaf(we, hi[1], acc.w);
#else
    acc.x = fmaf(we, f8dec<0>(wv), acc.x);
    acc.y = fmaf(we, f8dec<1>(wv), acc.y);
    acc.z = fmaf(we, f8dec<2>(wv), acc.z);
    acc.w = fmaf(we, f8dec<3>(wv), acc.w);
#endif
}

__device__ __forceinline__ int block_scan_incl(int v, int t) {
    int lane = t & 63, w = t >> 6;
    int sv = v;
    #pragma unroll
    for (int off = 1; off < 64; off <<= 1) {
        int u = __shfl_up(sv, off);
        if (lane >= off) sv += u;
    }
    __shared__ int ws_[4];
    if (lane == 63) ws_[w] = sv;
    __syncthreads();
    if (t == 0) {
        int a = 0;
        #pragma unroll
        for (int k = 0; k < 4; k++) { int x = ws_[k]; ws_[k] = a; a += x; }
    }
    __syncthreads();
    return sv + ws_[w];
}

// ================================================================ phase1: bucket histogram + prep (fused)
// blocks [0,256): bucket_count; blocks [256,...): x->bf16 + weight transposes.
__global__ __launch_bounds__(256) void phase1(const int* __restrict__ dstl,
                                              int E, int N, int NB,
                                              int* __restrict__ gHist,
                                              const float* __restrict__ x,
                                              unsigned short* __restrict__ xb, int n4x,
                                              const float* __restrict__ W1,
                                              const float* __restrict__ Ws1,
                                              const float* __restrict__ W2,
                                              const float* __restrict__ Ws2,
                                              const float* __restrict__ W3,
                                              unsigned short* __restrict__ Wcat1,
                                              unsigned short* __restrict__ Wcat2,
                                              unsigned short* __restrict__ W3t) {
    int t = threadIdx.x;
    if (blockIdx.x < 256) {
        __shared__ int h[256];
        h[t] = 0;
        __syncthreads();
        int Etot = E + N;
        for (int i = blockIdx.x * 256 + t; i < Etot; i += 256 * 256) {
            int d = (i < E) ? dstl[i] : (i - E);
            atomicAdd(&h[d >> BSH], 1);
        }
        __syncthreads();
        if (t < NB && h[t]) atomicAdd(&gHist[t], h[t]);
        return;
    }
    int i = (blockIdx.x - 256) * 256 + t;
    if (i < n4x) {
        float4 v = reinterpret_cast<const float4*>(x)[i];
        ushort4 o;
        o.x = f2bf(v.x); o.y = f2bf(v.y); o.z = f2bf(v.z); o.w = f2bf(v.w);
        reinterpret_cast<ushort4*>(xb)[i] = o;
        return;
    }
    int j = i - n4x;
    if (j < 32768) {
        int m = j >> 7, k = j & 127;
        Wcat1[j] = f2bf(W1[k * 256 + m]);
    } else if (j < 65536) {
        int q = j - 32768; int m = q >> 7, k = q & 127;
        Wcat1[32768 + q] = f2bf(Ws1[k * 256 + m]);
    } else if (j < 131072) {
        int q = j - 65536; int m = q >> 8, k = q & 255;
        Wcat2[q] = f2bf(W2[k * 256 + m]);
    } else if (j < 139264) {
        int q = j - 131072; int m = q >> 8, k = q & 255;
        Wcat2[65536 + q] = f2bf(Ws2[k * 32 + m]);
    } else if (j < 147456) {
        int q = j - 139264; int m = q >> 8, k = q & 255;
        W3t[q] = f2bf(W3[k * 32 + m]);
    }
}

// ================================================================ K3: bucket scatter (local scan of gHist)
__global__ __launch_bounds__(256) void bucket_scatter(const int* __restrict__ srcl,
                                                      const int* __restrict__ dstl,
                                                      int E, int N, int NB,
                                                      const int* __restrict__ gHist,
                                                      int* __restrict__ gCursor,
                                                      unsigned int* __restrict__ bktEdges) {
    __shared__ unsigned int stage[4096];
    __shared__ int lbase[256];
    __shared__ int hist[256];
    __shared__ int bexcl[257];
    __shared__ int curk[256];
    __shared__ int gbase[256];
    int t = threadIdx.x;
    int Etot = E + N;
    int begin = blockIdx.x * 4096;

    // local exclusive scan of gHist -> bucket bases
    int gv = (t < NB) ? gHist[t] : 0;
    int gincl = block_scan_incl(gv, t);
    lbase[t] = gincl - gv;
    __syncthreads();

    hist[t] = 0;
    __syncthreads();

    unsigned int ent[16];
    int eb[16];
    #pragma unroll
    for (int k = 0; k < 16; k++) {
        int i = begin + k * 256 + t;
        if (i < Etot) {
            int s, d;
            if (i < E) { s = srcl[i]; d = dstl[i]; }
            else       { s = d = i - E; }
            eb[k] = d >> BSH;
            ent[k] = ((unsigned int)s << BSH) | (unsigned int)(d & 255);
            atomicAdd(&hist[eb[k]], 1);
        } else eb[k] = -1;
    }
    __syncthreads();

    int v = hist[t];
    int incl = block_scan_incl(v, t);
    bexcl[t] = incl - v;
    curk[t] = incl - v;
    if (t == 255) bexcl[256] = incl;
    __syncthreads();

    #pragma unroll
    for (int k = 0; k < 16; k++) {
        if (eb[k] >= 0) {
            int slot = atomicAdd(&curk[eb[k]], 1);
            stage[slot] = ent[k];
        }
    }
    if (t < NB) {
        int cnt = hist[t];
        gbase[t] = cnt ? (lbase[t] + atomicAdd(&gCursor[t], cnt)) : 0;
    }
    __syncthreads();

    int total = bexcl[256];
    for (int p = t; p < total; p += 256) {
        int lo = 0, hi = NB - 1;
        while (lo < hi) {
            int mid = (lo + hi + 1) >> 1;
            if (bexcl[mid] <= p) lo = mid; else hi = mid - 1;
        }
        bktEdges[gbase[lo] + (p - bexcl[lo])] = stage[p];
    }
}

// ================================================================ K4: bucket -> fine CSR (local scan of gHist)
__global__ __launch_bounds__(256) void bucket_to_csr(const unsigned int* __restrict__ bktEdges,
                                                     const int* __restrict__ gHist,
                                                     int* __restrict__ indptr,
                                                     int* __restrict__ esrc,
                                                     int N, int NB, int Etot) {
    __shared__ int lbase[256];
    __shared__ int nh[256];
    __shared__ int ncur[256];
    __shared__ unsigned int stash[STASH_CAP];
    int b = blockIdx.x, t = threadIdx.x;

    int gv = (t < NB) ? gHist[t] : 0;
    int gincl = block_scan_incl(gv, t);
    lbase[t] = gincl - gv;
    __syncthreads();
    int base = lbase[b];
    int cnt = gHist[b];
    int nodeBase = b << BSH;

    nh[t] = 0;
    __syncthreads();
    for (int p = t; p < cnt; p += 256) {
        unsigned int e = bktEdges[base + p];
        if (p < STASH_CAP) stash[p] = e;
        atomicAdd(&nh[e & 255], 1);
    }
    __syncthreads();
    int v = nh[t];
    int incl = block_scan_incl(v, t);
    int excl = incl - v;
    ncur[t] = excl;
    if (nodeBase + t < N) indptr[nodeBase + t] = base + excl;
    __syncthreads();
    for (int p = t; p < cnt; p += 256) {
        unsigned int e = (p < STASH_CAP) ? stash[p] : bktEdges[base + p];
        int slot = atomicAdd(&ncur[e & 255], 1);
        esrc[base + slot] = (int)(e >> BSH);
    }
    if (b == 0 && t == 0) indptr[N] = Etot;
}

// ---------------------------------------------------------------- tiled MFMA GEMM (+fused alpha, H=8 or H=1)
// 128x128 tile, BK=32, double-buffered LDS via global_load_lds(16B).
// Epilogue: col < split -> optional bf16 outBf, optional fp8 outQ;
//           col >= split -> bf16 outSk + biasSk.
// Fused alpha: H=8 (NCtot>=128): per-head (32-col) sums via shfl within
// 16-lane groups -> asOut[row*8+h]. H=1 (NCtot==32): one head, warp_c==0
// only -> asOut[row].
__global__ __launch_bounds__(256) void gemm_tile(const unsigned short* __restrict__ A,
                                                 const unsigned short* __restrict__ Bt,
                                                 unsigned short* __restrict__ outBf,
                                                 unsigned char* __restrict__ outQ,
                                                 unsigned short* __restrict__ outSk,
                                                 const float* __restrict__ biasSk,
                                                 const float* __restrict__ aS,
                                                 const float* __restrict__ aD,
                                                 float* __restrict__ asOut,
                                                 float* __restrict__ adOut,
                                                 int M, int K, int NCtot, int split,
                                                 int ldBf, int ldSk) {
    __shared__ __align__(16) char smem[2][2][8192];
    int t = threadIdx.x;
    int w = t >> 6, lane = t & 63;
    int l16 = lane & 15, quad = lane >> 4;
    int warp_r = w >> 1, warp_c = w & 1;
    int rowBase = blockIdx.y * 128;
    int colBase = blockIdx.x * 128;

    int row_l = t & 127;
    int jchunk = t >> 7;
    int arow_st = rowBase + row_l; if (arow_st >= M) arow_st = M - 1;
    int bcol_st = colBase + row_l; if (bcol_st >= NCtot) bcol_st = NCtot - 1;
    const unsigned short* aRow = A + (size_t)arow_st * K;
    const unsigned short* bRow = Bt + (size_t)bcol_st * K;

    f32x4 acc[4][4];
    #pragma unroll
    for (int i = 0; i < 4; i++)
        #pragma unroll
        for (int j = 0; j < 4; j++) acc[i][j] = (f32x4){0.f, 0.f, 0.f, 0.f};

    auto stage = [&](int buf, int k0) {
        #pragma unroll
        for (int j = 0; j < 2; j++) {
            int chunk = j * 2 + jchunk;
            gload_lds16(aRow + k0 + chunk * 8, &smem[buf][0][(size_t)j * 4096 + (size_t)t * 16]);
            gload_lds16(bRow + k0 + chunk * 8, &smem[buf][1][(size_t)j * 4096 + (size_t)t * 16]);
        }
    };

    stage(0, 0);
    __syncthreads();
    int niter = K >> 5;
    for (int it = 0; it < niter; ++it) {
        if (it + 1 < niter) stage((it + 1) & 1, (it + 1) << 5);
        const char* Ab = &smem[it & 1][0][0];
        const char* Bb = &smem[it & 1][1][0];
        bf16x8 a[4], b[4];
        #pragma unroll
        for (int i = 0; i < 4; i++)
            a[i] = *reinterpret_cast<const bf16x8*>(Ab + quad * 2048 + (warp_r * 64 + i * 16 + l16) * 16);
        #pragma unroll
        for (int j = 0; j < 4; j++)
            b[j] = *reinterpret_cast<const bf16x8*>(Bb + quad * 2048 + (warp_c * 64 + j * 16 + l16) * 16);
        #pragma unroll
        for (int i = 0; i < 4; i++)
            #pragma unroll
            for (int j = 0; j < 4; j++)
                acc[i][j] = __builtin_amdgcn_mfma_f32_16x16x32_bf16(a[i], b[j], acc[i][j], 0, 0, 0);
        __syncthreads();
    }

    // ---- fused alpha
    if (aS && colBase < split) {
        if (NCtot >= 128) {          // H=8: two heads per 64-col wave region
            int c0 = colBase + warp_c * 64 + l16;
            int hbase = (colBase + warp_c * 64) >> 5;
            float as0 = aS[c0],      ad0 = aD[c0];
            float as1 = aS[c0 + 16], ad1 = aD[c0 + 16];
            float as2 = aS[c0 + 32], ad2 = aD[c0 + 32];
            float as3 = aS[c0 + 48], ad3 = aD[c0 + 48];
            #pragma unroll
            for (int i = 0; i < 4; i++) {
                #pragma unroll
                for (int r = 0; r < 4; r++) {
                    float va0 = acc[i][0][r] * as0 + acc[i][1][r] * as1;
                    float vd0 = acc[i][0][r] * ad0 + acc[i][1][r] * ad1;
                    float va1 = acc[i][2][r] * as2 + acc[i][3][r] * as3;
                    float vd1 = acc[i][2][r] * ad2 + acc[i][3][r] * ad3;
                    #pragma unroll
                    for (int off = 1; off < 16; off <<= 1) {
                        va0 += __shfl_xor(va0, off);
                        vd0 += __shfl_xor(vd0, off);
                        va1 += __shfl_xor(va1, off);
                        vd1 += __shfl_xor(vd1, off);
                    }
                    int row = rowBase + warp_r * 64 + i * 16 + quad * 4 + r;
                    if (l16 == 0 && row < M) {
                        asOut[row * 8 + hbase]     = va0;
                        adOut[row * 8 + hbase]     = vd0;
                        asOut[row * 8 + hbase + 1] = va1;
                        adOut[row * 8 + hbase + 1] = vd1;
                    }
                }
            }
        } else if (warp_c == 0) {    // H=1: cols 0..31 in fragments j=0,1
            float as0 = aS[l16],      ad0 = aD[l16];
            float as1 = aS[l16 + 16], ad1 = aD[l16 + 16];
            #pragma unroll
            for (int i = 0; i < 4; i++) {
                #pragma unroll
                for (int r = 0; r < 4; r++) {
                    float va = acc[i][0][r] * as0 + acc[i][1][r] * as1;
                    float vd = acc[i][0][r] * ad0 + acc[i][1][r] * ad1;
                    #pragma unroll
                    for (int off = 1; off < 16; off <<= 1) {
                        va += __shfl_xor(va, off);
                        vd += __shfl_xor(vd, off);
                    }
                    int row = rowBase + warp_r * 64 + i * 16 + quad * 4 + r;
                    if (l16 == 0 && row < M) {
                        asOut[row] = va;
                        adOut[row] = vd;
                    }
                }
            }
        }
    }

    #pragma unroll
    for (int i = 0; i < 4; i++) {
        #pragma unroll
        for (int r = 0; r < 4; r++) {
            int row = rowBase + warp_r * 64 + i * 16 + quad * 4 + r;
            if (row >= M) continue;
            #pragma unroll
            for (int j = 0; j < 4; j++) {
                int c = colBase + warp_c * 64 + j * 16 + l16;
                if (c >= NCtot) continue;
                float v = acc[i][j][r];
                if (c < split) {
                    if (outBf) outBf[(size_t)row * ldBf + c] = f2bf(v);
                    if (outQ)  outQ[(size_t)row * ldBf + c] = f8enc(v);
                } else {
                    outSk[(size_t)row * ldSk + (c - split)] = f2bf(v + biasSk[c - split]);
                }
            }
        }
    }
}

// ---------------------------------------------------------------- aggregation H=8,C=32 (fp8 gather)
template <int MODE>
__global__ __launch_bounds__(256) void agg256(const unsigned char* __restrict__ hq,
                                              const float* __restrict__ as,
                                              const float* __restrict__ ad,
                                              const int* __restrict__ indptr,
                                              const int* __restrict__ esrc,
                                              const float* __restrict__ bias,
                                              const float* __restrict__ bn_g,
                                              const float* __restrict__ bn_b,
                                              const float* __restrict__ bn_m,
                                              const float* __restrict__ bn_v,
                                              const unsigned short* __restrict__ skip,
                                              unsigned short* __restrict__ out, int N) {
    int t = threadIdx.x;
    int n = blockIdx.x * 4 + (t >> 6);
    if (n >= N) return;
    int lane = t & 63;
    int e_sub = lane >> 3, h_sub = lane & 7;
    int ch_head = lane >> 3;
    int lane4 = lane * 4;
    int start = indptr[n], end = indptr[n + 1];
    int cnt = end - start;

    float adh = ad[n * 8 + h_sub];

    float4 acc = make_float4(0.f, 0.f, 0.f, 0.f);
    float sm = 0.f;
    int nfull = cnt & ~7;
    int i0 = start;
    int s_l = 0; float w8 = 0.f;
    if (nfull) {
        s_l = esrc[i0 + e_sub];
        w8 = __expf(lrelu(as[s_l * 8 + h_sub] + adh));
    }
    while (i0 < start + nfull) {
        int s_cur = s_l;
        float w_cur = w8;
        i0 += 8;
        if (i0 < start + nfull) {
            s_l = esrc[i0 + e_sub];
            w8 = __expf(lrelu(as[s_l * 8 + h_sub] + adh));
        }
        sm += w_cur;
        unsigned int hv[8];
        #pragma unroll
        for (int e = 0; e < 8; e++) {
            int se = __shfl(s_cur, e * 8);
            hv[e] = *reinterpret_cast<const unsigned int*>(&hq[(size_t)se * 256 + lane4]);
        }
        #pragma unroll
        for (int e = 0; e < 8; e++) {
            float we = __shfl(w_cur, e * 8 + ch_head);
            fma_f8x4(we, hv[e], acc);
        }
    }
    int rem = cnt - nfull;
    if (rem) {
        int idx = i0 + e_sub;
        int s_r = esrc[idx < end ? idx : end - 1];
        float w_r = (idx < end) ? __expf(lrelu(as[s_r * 8 + h_sub] + adh)) : 0.f;
        sm += w_r;
        #pragma unroll
        for (int e = 0; e < 8; e++) {
            if (e < rem) {
                int se = __shfl(s_r, e * 8);
                float we = __shfl(w_r, e * 8 + ch_head);
                unsigned int hv = *reinterpret_cast<const unsigned int*>(&hq[(size_t)se * 256 + lane4]);
                fma_f8x4(we, hv, acc);
            }
        }
    }
    #pragma unroll
    for (int off = 8; off < 64; off <<= 1) sm += __shfl_xor(sm, off);
    float il = 1.f / (sm + 1e-16f);
    float il_c = __shfl(il, ch_head);

    float4 bv  = *reinterpret_cast<const float4*>(&bias[lane4]);
    float4 gv  = *reinterpret_cast<const float4*>(&bn_g[lane4]);
    float4 bbv = *reinterpret_cast<const float4*>(&bn_b[lane4]);
    float4 mv  = *reinterpret_cast<const float4*>(&bn_m[lane4]);
    float4 vv  = *reinterpret_cast<const float4*>(&bn_v[lane4]);
    float o[4] = {acc.x * il_c + bv.x, acc.y * il_c + bv.y,
                  acc.z * il_c + bv.z, acc.w * il_c + bv.w};
    float g[4] = {gv.x, gv.y, gv.z, gv.w}, bb[4] = {bbv.x, bbv.y, bbv.z, bbv.w};
    float m[4] = {mv.x, mv.y, mv.z, mv.w}, vr[4] = {vv.x, vv.y, vv.z, vv.w};
    float sk[4] = {0.f, 0.f, 0.f, 0.f};
    if (MODE == 1) {
        ushort4 s4 = *reinterpret_cast<const ushort4*>(&skip[(size_t)n * 256 + lane4]);
        sk[0] = bf2f(s4.x); sk[1] = bf2f(s4.y); sk[2] = bf2f(s4.z); sk[3] = bf2f(s4.w);
    }
    ushort4 res;
    unsigned short* rp = &res.x;
    #pragma unroll
    for (int j = 0; j < 4; j++) {
        float val = (o[j] - m[j]) * rsqrtf(vr[j] + BN_EPS) * g[j] + bb[j];
        val = val > 0.f ? val : (__expf(val) - 1.f);
        val += sk[j];
        rp[j] = f2bf(val);
    }
    *reinterpret_cast<ushort4*>(&out[(size_t)n * 256 + lane4]) = res;
}

// ---------------------------------------------------------------- aggregation H=1,C=32
__global__ __launch_bounds__(256) void agg32(const unsigned short* __restrict__ h3,
                                             const float* __restrict__ as,
                                             const float* __restrict__ ad,
                                             const int* __restrict__ indptr,
                                             const int* __restrict__ esrc,
                                             const float* __restrict__ b3,
                                             const unsigned short* __restrict__ xs,
                                             float* __restrict__ out, int N) {
    int t = threadIdx.x;
    int n = blockIdx.x * 4 + (t >> 6);
    if (n >= N) return;
    int lane = t & 63;
    int e_sub = lane >> 3, c4 = (lane & 7) * 4;
    int start = indptr[n], end = indptr[n + 1];
    float adn = ad[n];

    float4 acc = make_float4(0.f, 0.f, 0.f, 0.f);
    float sm = 0.f;
    int i0 = start;
    for (; i0 + 16 <= end; i0 += 16) {
        int sA = esrc[i0 + e_sub];
        int sB = esrc[i0 + 8 + e_sub];
        float wA = __expf(lrelu(as[sA] + adn));
        float wB = __expf(lrelu(as[sB] + adn));
        sm += wA + wB;
        ushort4 hA = *reinterpret_cast<const ushort4*>(&h3[(size_t)sA * 32 + c4]);
        ushort4 hB = *reinterpret_cast<const ushort4*>(&h3[(size_t)sB * 32 + c4]);
        acc.x = fmaf(wA, bf2f(hA.x), acc.x); acc.y = fmaf(wA, bf2f(hA.y), acc.y);
        acc.z = fmaf(wA, bf2f(hA.z), acc.z); acc.w = fmaf(wA, bf2f(hA.w), acc.w);
        acc.x = fmaf(wB, bf2f(hB.x), acc.x); acc.y = fmaf(wB, bf2f(hB.y), acc.y);
        acc.z = fmaf(wB, bf2f(hB.z), acc.z); acc.w = fmaf(wB, bf2f(hB.w), acc.w);
    }
    for (; i0 < end; i0 += 8) {
        int idx = i0 + e_sub;
        bool valid = idx < end;
        if (valid) {
            int s = esrc[idx];
            float w = __expf(lrelu(as[s] + adn));
            sm += w;
            ushort4 hv = *reinterpret_cast<const ushort4*>(&h3[(size_t)s * 32 + c4]);
            acc.x = fmaf(w, bf2f(hv.x), acc.x);
            acc.y = fmaf(w, bf2f(hv.y), acc.y);
            acc.z = fmaf(w, bf2f(hv.z), acc.z);
            acc.w = fmaf(w, bf2f(hv.w), acc.w);
        }
    }
    #pragma unroll
    for (int off = 8; off < 64; off <<= 1) {
        sm    += __shfl_xor(sm, off);
        acc.x += __shfl_xor(acc.x, off);
        acc.y += __shfl_xor(acc.y, off);
        acc.z += __shfl_xor(acc.z, off);
        acc.w += __shfl_xor(acc.w, off);
    }
    if (e_sub == 0) {
        float il = 1.f / (sm + 1e-16f);
        float4 bv = *reinterpret_cast<const float4*>(&b3[c4]);
        ushort4 xv = *reinterpret_cast<const ushort4*>(&xs[(size_t)n * 32 + c4]);
        float4 o;
        o.x = acc.x * il + bv.x + bf2f(xv.x);
        o.y = acc.y * il + bv.y + bf2f(xv.y);
        o.z = acc.z * il + bv.z + bf2f(xv.z);
        o.w = acc.w * il + bv.w + bf2f(xv.w);
        *reinterpret_cast<float4*>(&out[(size_t)n * 32 + c4]) = o;
    }
}

// ---------------------------------------------------------------- launch
extern "C" void kernel_launch(void* const* d_in, const int* in_sizes, int n_in,
                              void* d_out, int out_size, void* d_ws, size_t ws_size,
                              hipStream_t stream) {
    const float* x      = (const float*)d_in[0];
    const int*   eidx   = (const int*)  d_in[1];
    const float* W1     = (const float*)d_in[2];
    const float* a_src1 = (const float*)d_in[3];
    const float* a_dst1 = (const float*)d_in[4];
    const float* b1     = (const float*)d_in[5];
    const float* bn1_g  = (const float*)d_in[6];
    const float* bn1_b  = (const float*)d_in[7];
    const float* bn1_m  = (const float*)d_in[8];
    const float* bn1_v  = (const float*)d_in[9];
    const float* W2     = (const float*)d_in[10];
    const float* a_src2 = (const float*)d_in[11];
    const float* a_dst2 = (const float*)d_in[12];
    const float* b2     = (const float*)d_in[13];
    const float* bn2_g  = (const float*)d_in[14];
    const float* bn2_b  = (const float*)d_in[15];
    const float* bn2_m  = (const float*)d_in[16];
    const float* bn2_v  = (const float*)d_in[17];
    const float* W3     = (const float*)d_in[18];
    const float* a_src3 = (const float*)d_in[19];
    const float* a_dst3 = (const float*)d_in[20];
    const float* b3     = (const float*)d_in[21];
    const float* Ws1    = (const float*)d_in[22];
    const float* bs1    = (const float*)d_in[23];
    const float* Ws2    = (const float*)d_in[24];
    const float* bs2    = (const float*)d_in[25];

    const int N = in_sizes[0] / 128;   // 50000
    const int E = in_sizes[1] / 2;     // 800000
    const int Etot = E + N;
    const int NB = (N + 255) >> 8;     // 196 buckets
    const int* srcl = eidx;
    const int* dstl = eidx + E;

    char* ws = (char*)d_ws;
    size_t off = 0;
    auto alloc = [&](size_t bytes) -> void* {
        void* p = ws + off;
        off += (bytes + 255) & ~(size_t)255;
        return p;
    };
    unsigned short* xb    = (unsigned short*)alloc((size_t)N * 128 * 2);
    unsigned short* feat  = (unsigned short*)alloc((size_t)N * 256 * 2); // x0 skip (bf16)
    unsigned char*  hq    = (unsigned char*)alloc((size_t)N * 256);     // fp8 h for gathers
    unsigned short* h2b   = (unsigned short*)alloc((size_t)N * 256 * 2); // layer-1 agg out
    unsigned short* featb = (unsigned short*)alloc((size_t)N * 256 * 2); // layer-2 agg out
    unsigned short* xsbuf = (unsigned short*)alloc((size_t)N * 32 * 2);  // xs skip (bf16)
    unsigned short* h3b   = (unsigned short*)alloc((size_t)N * 32 * 2);
    float*          asb   = (float*)alloc((size_t)N * 8 * 4);
    float*          adb   = (float*)alloc((size_t)N * 8 * 4);
    unsigned short* Wcat1 = (unsigned short*)alloc((size_t)512 * 128 * 2); // [W1t; Ws1t]
    unsigned short* Wcat2 = (unsigned short*)alloc((size_t)288 * 256 * 2); // [W2t; Ws2t]
    unsigned short* W3t   = (unsigned short*)alloc((size_t)32 * 256 * 2);
    int* gHC     = (int*)alloc(512 * 4);          // [gHist(256) | gCursor(256)]
    int* gHist   = gHC;
    int* gCursor = gHC + 256;
    unsigned int* bktEdges = (unsigned int*)alloc((size_t)Etot * 4);
    int* indptr  = (int*)alloc((size_t)(N + 1) * 4);
    int* esrc    = (int*)alloc((size_t)Etot * 4);
    (void)ws_size; (void)n_in; (void)out_size;

    // ---- CSR build (bucketed multi-split, scans recomputed locally)
    hipMemsetAsync(gHC, 0, 512 * 4, stream);
    int n4x = N * 128 / 4;
    int prepBlocks = (n4x + 147456 + 255) / 256;
    phase1<<<256 + prepBlocks, 256, 0, stream>>>(dstl, E, N, NB, gHist,
                                                 x, xb, n4x,
                                                 W1, Ws1, W2, Ws2, W3,
                                                 Wcat1, Wcat2, W3t);
    bucket_scatter<<<(Etot + 4095) / 4096, 256, 0, stream>>>(srcl, dstl, E, N, NB,
                                                             gHist, gCursor, bktEdges);
    bucket_to_csr<<<NB, 256, 0, stream>>>(bktEdges, gHist, indptr, esrc, N, NB, Etot);

    int gy128 = (N + 127) / 128;
    int gn4 = (N + 3) / 4;

    // ---- layer 1: fused [h1 | x0] = x @ [W1 | Ws1], alpha fused in epilogue
    gemm_tile<<<dim3(4, gy128), 256, 0, stream>>>(xb, Wcat1, nullptr, hq, feat, bs1,
                                                  a_src1, a_dst1, asb, adb,
                                                  N, 128, 512, 256, 256, 256);
    agg256<1><<<gn4, 256, 0, stream>>>(hq, asb, adb, indptr, esrc, b1,
                                       bn1_g, bn1_b, bn1_m, bn1_v, feat, h2b, N);

    // ---- layer 2: fused [h2 | xs] = h @ [W2 | Ws2], alpha fused in epilogue
    gemm_tile<<<dim3(3, gy128), 256, 0, stream>>>(h2b, Wcat2, nullptr, hq, xsbuf, bs2,
                                                  a_src2, a_dst2, asb, adb,
                                                  N, 256, 288, 256, 256, 32);
    agg256<0><<<gn4, 256, 0, stream>>>(hq, asb, adb, indptr, esrc, b2,
                                       bn2_g, bn2_b, bn2_m, bn2_v, nullptr, featb, N);

    // ---- layer 3: tiled GEMM (NCtot=32) with H=1 alpha fused
    gemm_tile<<<dim3(1, gy128), 256, 0, stream>>>(featb, W3t, h3b, nullptr, h3b, nullptr,
                                                  a_src3, a_dst3, asb, adb,
                                                  N, 256, 32, 32, 32, 32);
    agg32<<<gn4, 256, 0, stream>>>(h3b, asb, adb, indptr, esrc, b3, xsbuf,
                                   (float*)d_out, N);
}